// Round 2
// baseline (3527.100 us; speedup 1.0000x reference)
//
#include <hip/hip_runtime.h>
#include <hip/hip_bf16.h>

using bf16 = __hip_bfloat16;

#define DEVFN __device__ __forceinline__

DEVFN float b2f(bf16 v) { return __bfloat162float(v); }
DEVFN bf16  f2b(float v) { return __float2bfloat16(v); }
DEVFN float us2f(unsigned short u) { union { unsigned int i; float f; } x; x.i = ((unsigned int)u) << 16; return x.f; }
DEVFN void unp8(uint4 u, float* f) {
  f[0]=us2f(u.x & 0xffffu); f[1]=us2f(u.x >> 16);
  f[2]=us2f(u.y & 0xffffu); f[3]=us2f(u.y >> 16);
  f[4]=us2f(u.z & 0xffffu); f[5]=us2f(u.z >> 16);
  f[6]=us2f(u.w & 0xffffu); f[7]=us2f(u.w >> 16);
}

// ---------------- workspace layout (float element offsets) ----------------
// total required: 38,453,288 floats = ~147 MiB
static constexpr size_t OF_PATCH = 0;          // 8192*588 f32
static constexpr size_t OF_E     = 4816896;    // 8192*512
static constexpr size_t OF_XN    = 9011200;    // 8192*512
static constexpr size_t OF_Q     = 13205504;   // 8192*512
static constexpr size_t OF_K     = 17399808;
static constexpr size_t OF_V     = 21594112;
static constexpr size_t OF_CTX   = 25788416;
static constexpr size_t OF_O1    = 29982720;
static constexpr size_t OF_O2    = 34177024;
static constexpr size_t OF_FV    = 38371328;   // 32*512
static constexpr size_t OF_GATES = 38387712;   // 8192*2
static constexpr size_t OF_IMPS  = 38404096;   // 8 f32   (memset with CNT: 64B)
static constexpr size_t OF_CNT   = 38404104;   // 8 i32
static constexpr size_t OF_BASE  = 38404112;   // 8 i32
static constexpr size_t OF_CURS  = 38404120;   // 8 i32
static constexpr size_t OF_LOSS  = 38404128;   // 1 f32 (+pad)
static constexpr size_t OF_TOPI  = 38404136;   // 8192*2 i32
static constexpr size_t OF_RPOS  = 38420520;   // 8192*2 i32
static constexpr size_t OF_RLIST = 38436904;   // 16384 i32
// Overlays: H (bf16, 16384x2048) on [OF_Q, OF_O1) bytes (exactly 64 MiB);
//           YB (f32, 16384x512) on [0, 8388608) floats (inside patches+e, both dead).

// ---------------- patchify: x[B,3,224,224] -> patches[8192,588] ----------------
__global__ __launch_bounds__(256) void k_patchify(const float* __restrict__ x, float* __restrict__ patches) {
  int idx = blockIdx.x * 256 + threadIdx.x;
  if (idx >= 8192 * 588) return;
  int row = idx / 588, j = idx - row * 588;
  int b = row >> 8, s = row & 255;
  int hh = s >> 4, ww = s & 15;
  int c = j % 3, tt = j / 3;
  int p2 = tt % 14, p1 = tt / 14;
  int src = ((b * 3 + c) * 224 + hh * 14 + p1) * 224 + (ww * 14 + p2);
  patches[idx] = x[src];
}

// ---------------- generic tiled GEMM: C[M,N] = A(f32)[M,K] @ B(f32)[K,N] ----------------
// EPI 0: + bias + pos[(m%256),n]   (patch embed)
// EPI 1: + bias
// EPI 2: + bias, accumulate into existing C (residual add)
template<int EPI>
__global__ __launch_bounds__(256) void k_gemm(const float* __restrict__ A, const float* __restrict__ Bw,
    float* __restrict__ C, int M, int N, int K,
    const float* __restrict__ bias, const float* __restrict__ pos)
{
  __shared__ float As[16][132];
  __shared__ float Bs[16][132];
  const int t = threadIdx.x;
  const int m0 = blockIdx.y * 128, n0 = blockIdx.x * 128;
  const int tx = t & 15, ty = t >> 4;
  const int ar = t >> 1, ac = (t & 1) * 8;
  const int br = t >> 4, bc = (t & 15) * 8;
  float acc[8][8];
#pragma unroll
  for (int i = 0; i < 8; i++)
#pragma unroll
    for (int j = 0; j < 8; j++) acc[i][j] = 0.f;

  for (int k0 = 0; k0 < K; k0 += 16) {
    if (k0 + ac + 8 <= K) {
      const float* ap = A + (size_t)(m0 + ar) * K + (k0 + ac);
      float4 a0 = *(const float4*)ap;
      float4 a1 = *(const float4*)(ap + 4);
      As[ac+0][ar]=a0.x; As[ac+1][ar]=a0.y; As[ac+2][ar]=a0.z; As[ac+3][ar]=a0.w;
      As[ac+4][ar]=a1.x; As[ac+5][ar]=a1.y; As[ac+6][ar]=a1.z; As[ac+7][ar]=a1.w;
    } else {
      const float* ap = A + (size_t)(m0 + ar) * K;
#pragma unroll
      for (int i = 0; i < 8; i++) { int kk = k0 + ac + i; As[ac+i][ar] = (kk < K) ? ap[kk] : 0.f; }
    }
    {
      int kk = k0 + br;
      if (kk < K) {
        const float* bp = Bw + (size_t)kk * N + (n0 + bc);
        float4 b0 = *(const float4*)bp;
        float4 b1 = *(const float4*)(bp + 4);
        Bs[br][bc+0]=b0.x; Bs[br][bc+1]=b0.y; Bs[br][bc+2]=b0.z; Bs[br][bc+3]=b0.w;
        Bs[br][bc+4]=b1.x; Bs[br][bc+5]=b1.y; Bs[br][bc+6]=b1.z; Bs[br][bc+7]=b1.w;
      } else {
#pragma unroll
        for (int i = 0; i < 8; i++) Bs[br][bc+i] = 0.f;
      }
    }
    __syncthreads();
#pragma unroll
    for (int kk = 0; kk < 16; kk++) {
      float4 a0 = *(const float4*)&As[kk][ty*8];
      float4 a1 = *(const float4*)&As[kk][ty*8+4];
      float4 b0 = *(const float4*)&Bs[kk][tx*8];
      float4 b1 = *(const float4*)&Bs[kk][tx*8+4];
      float av[8] = {a0.x,a0.y,a0.z,a0.w,a1.x,a1.y,a1.z,a1.w};
      float bv[8] = {b0.x,b0.y,b0.z,b0.w,b1.x,b1.y,b1.z,b1.w};
#pragma unroll
      for (int i = 0; i < 8; i++)
#pragma unroll
        for (int j = 0; j < 8; j++) acc[i][j] = fmaf(av[i], bv[j], acc[i][j]);
    }
    __syncthreads();
  }
#pragma unroll
  for (int i = 0; i < 8; i++) {
    int m = m0 + ty * 8 + i;
    float* cp = C + (size_t)m * N + (n0 + tx * 8);
    float vals[8];
#pragma unroll
    for (int j = 0; j < 8; j++) {
      int n = n0 + tx * 8 + j;
      float v = acc[i][j] + bias[n];
      if (EPI == 0) v += pos[(size_t)(m & 255) * 512 + n];
      vals[j] = v;
    }
    if (EPI == 2) {
      float4 o0 = *(const float4*)cp;
      float4 o1 = *(const float4*)(cp + 4);
      vals[0]+=o0.x; vals[1]+=o0.y; vals[2]+=o0.z; vals[3]+=o0.w;
      vals[4]+=o1.x; vals[5]+=o1.y; vals[6]+=o1.z; vals[7]+=o1.w;
    }
    float4 s0 = {vals[0],vals[1],vals[2],vals[3]};
    float4 s1 = {vals[4],vals[5],vals[6],vals[7]};
    *(float4*)cp = s0; *(float4*)(cp + 4) = s1;
  }
}

// ---------------- LayerNorm over D=512 ----------------
__global__ __launch_bounds__(256) void k_ln(const float* __restrict__ X, float* __restrict__ Y,
    const float* __restrict__ g, const float* __restrict__ b)
{
  __shared__ float red[256];
  const int row = blockIdx.x;
  const int t = threadIdx.x;
  const float* xr = X + (size_t)row * 512;
  float x0 = xr[t], x1 = xr[t + 256];
  red[t] = x0 + x1;
  __syncthreads();
  for (int s = 128; s > 0; s >>= 1) { if (t < s) red[t] += red[t + s]; __syncthreads(); }
  float mean = red[0] * (1.f / 512.f);
  __syncthreads();
  float d0 = x0 - mean, d1 = x1 - mean;
  red[t] = d0 * d0 + d1 * d1;
  __syncthreads();
  for (int s = 128; s > 0; s >>= 1) { if (t < s) red[t] += red[t + s]; __syncthreads(); }
  float rs = 1.f / sqrtf(red[0] * (1.f / 512.f) + 1e-5f);
  float* yr = Y + (size_t)row * 512;
  yr[t]       = d0 * rs * g[t]       + b[t];
  yr[t + 256] = d1 * rs * g[t + 256] + b[t + 256];
}

// ---------------- attention: 16 q-rows per block, 8 heads, writes ctx + attn_w ----------------
__global__ __launch_bounds__(256) void k_attn(const float* __restrict__ Q, const float* __restrict__ Kb,
    const float* __restrict__ V, float* __restrict__ CTXp, float* __restrict__ AW)
{
  __shared__ float qs[16][65];
  __shared__ float kt[64][65];
  __shared__ float Sm[16][257];
  __shared__ float ab[16][257];
  const int t = threadIdx.x;
  const int b = blockIdx.y, qt = blockIdx.x;
  const int qi0 = qt * 16;
  for (int i = t; i < 4096; i += 256) ab[i >> 8][i & 255] = 0.f;

  const int sr = t >> 4, sc4 = (t & 15) * 4;
  const size_t qbase = (size_t)(b * 256 + qi0) * 512;

  for (int h = 0; h < 8; h++) {
    {
      float4 qv = *(const float4*)(Q + qbase + (size_t)sr * 512 + h * 64 + sc4);
      qs[sr][sc4]=qv.x; qs[sr][sc4+1]=qv.y; qs[sr][sc4+2]=qv.z; qs[sr][sc4+3]=qv.w;
    }
    for (int kc = 0; kc < 4; kc++) {
      __syncthreads();
#pragma unroll
      for (int i = 0; i < 4; i++) {
        int rr = sr + i * 16;
        float4 kv = *(const float4*)(Kb + (size_t)(b * 256 + kc * 64 + rr) * 512 + h * 64 + sc4);
        kt[rr][sc4]=kv.x; kt[rr][sc4+1]=kv.y; kt[rr][sc4+2]=kv.z; kt[rr][sc4+3]=kv.w;
      }
      __syncthreads();
      const int q_l = t & 15, kg = t >> 4;
#pragma unroll
      for (int j = 0; j < 4; j++) {
        int k_l = kg * 4 + j;
        float s = 0.f;
#pragma unroll
        for (int d = 0; d < 64; d++) s = fmaf(qs[q_l][d], kt[k_l][d], s);
        Sm[q_l][kc * 64 + k_l] = s * 0.125f;
      }
    }
    __syncthreads();
    {
      const int row = t >> 4, seg = t & 15;
      float vals[16];
      float vmax = -1e30f;
#pragma unroll
      for (int i = 0; i < 16; i++) { vals[i] = Sm[row][seg * 16 + i]; vmax = fmaxf(vmax, vals[i]); }
#pragma unroll
      for (int mk = 1; mk < 16; mk <<= 1) vmax = fmaxf(vmax, __shfl_xor(vmax, mk, 64));
      float ssum = 0.f;
#pragma unroll
      for (int i = 0; i < 16; i++) { vals[i] = __expf(vals[i] - vmax); ssum += vals[i]; }
#pragma unroll
      for (int mk = 1; mk < 16; mk <<= 1) ssum += __shfl_xor(ssum, mk, 64);
      float inv = 1.f / ssum;
#pragma unroll
      for (int i = 0; i < 16; i++) {
        float p = vals[i] * inv;
        Sm[row][seg * 16 + i] = p;
        ab[row][seg * 16 + i] += 0.125f * p;
      }
    }
    float acc0 = 0.f, acc1 = 0.f, acc2 = 0.f, acc3 = 0.f;
    const int d = t & 63, qg = t >> 6;
    for (int vc = 0; vc < 4; vc++) {
      __syncthreads();
#pragma unroll
      for (int i = 0; i < 4; i++) {
        int rr = sr + i * 16;
        float4 vv = *(const float4*)(V + (size_t)(b * 256 + vc * 64 + rr) * 512 + h * 64 + sc4);
        kt[rr][sc4]=vv.x; kt[rr][sc4+1]=vv.y; kt[rr][sc4+2]=vv.z; kt[rr][sc4+3]=vv.w;
      }
      __syncthreads();
#pragma unroll
      for (int kk = 0; kk < 64; kk++) {
        float vv = kt[kk][d];
        acc0 = fmaf(Sm[qg    ][vc * 64 + kk], vv, acc0);
        acc1 = fmaf(Sm[qg + 4][vc * 64 + kk], vv, acc1);
        acc2 = fmaf(Sm[qg + 8][vc * 64 + kk], vv, acc2);
        acc3 = fmaf(Sm[qg +12][vc * 64 + kk], vv, acc3);
      }
    }
    {
      float* cb = CTXp + qbase + (size_t)h * 64 + d;
      cb[(size_t)(qg    ) * 512] = acc0;
      cb[(size_t)(qg + 4) * 512] = acc1;
      cb[(size_t)(qg + 8) * 512] = acc2;
      cb[(size_t)(qg +12) * 512] = acc3;
    }
  }
  __syncthreads();
  {
    const int row = t >> 4, seg = t & 15;
    float vals[16]; float vmax = -1e30f;
#pragma unroll
    for (int i = 0; i < 16; i++) { vals[i] = ab[row][seg * 16 + i]; vmax = fmaxf(vmax, vals[i]); }
#pragma unroll
    for (int mk = 1; mk < 16; mk <<= 1) vmax = fmaxf(vmax, __shfl_xor(vmax, mk, 64));
    float ssum = 0.f;
#pragma unroll
    for (int i = 0; i < 16; i++) { vals[i] = __expf(vals[i] - vmax); ssum += vals[i]; }
#pragma unroll
    for (int mk = 1; mk < 16; mk <<= 1) ssum += __shfl_xor(ssum, mk, 64);
    float inv = 1.f / ssum;
    float* orow = AW + (size_t)(b * 256 + qi0 + row) * 256 + seg * 16;
#pragma unroll
    for (int i = 0; i < 16; i++) orow[i] = vals[i] * inv;
  }
}

// ---------------- router: softmax over 8 experts, top-2, imp/cnt stats ----------------
DEVFN int rwidx(int k, int e) { return k * 8 + e + (k >> 6) * 4; }  // skew to break LDS bank aliasing

__global__ __launch_bounds__(256) void k_router(const float* __restrict__ XNp, const float* __restrict__ rw,
    const float* __restrict__ rb, float* __restrict__ gates, int* __restrict__ topi,
    int* __restrict__ cnt, float* __restrict__ imps)
{
  __shared__ float rws[4128];
  const int t = threadIdx.x;
  for (int i = t; i < 4096; i += 256) rws[rwidx(i >> 3, i & 7)] = rw[i];
  __syncthreads();
  const int w = t >> 6, l = t & 63;
  const int e = l & 7, ch = l >> 3;
  float impAcc = 0.f; int cntAcc = 0;
  const int row0 = blockIdx.x * 256 + w * 64;
  for (int r = 0; r < 64; r++) {
    const int row = row0 + r;
    const float* xr = XNp + (size_t)row * 512 + ch * 64;
    float s = 0.f;
#pragma unroll 8
    for (int j = 0; j < 64; j++) s = fmaf(xr[j], rws[rwidx(ch * 64 + j, e)], s);
    s += __shfl_xor(s, 8, 64);
    s += __shfl_xor(s, 16, 64);
    s += __shfl_xor(s, 32, 64);
    s += rb[e];
    float p[8];
#pragma unroll
    for (int i = 0; i < 8; i++) p[i] = __shfl(s, (l & 56) | i, 64);
    float mx = p[0];
#pragma unroll
    for (int i = 1; i < 8; i++) mx = fmaxf(mx, p[i]);
    float sum = 0.f;
#pragma unroll
    for (int i = 0; i < 8; i++) { p[i] = __expf(p[i] - mx); sum += p[i]; }
    float inv = 1.f / sum;
#pragma unroll
    for (int i = 0; i < 8; i++) p[i] *= inv;
    int t0 = 0; float v0 = p[0];
#pragma unroll
    for (int i = 1; i < 8; i++) if (p[i] > v0) { v0 = p[i]; t0 = i; }
    int t1 = -1; float v1 = -1.f;
#pragma unroll
    for (int i = 0; i < 8; i++) if (i != t0 && p[i] > v1) { v1 = p[i]; t1 = i; }
    if (l < 8) { impAcc += p[e]; cntAcc += (t0 == e) + (t1 == e); }
    if (l == 0) {
      gates[(size_t)row * 2] = v0; gates[(size_t)row * 2 + 1] = v1;
      topi[(size_t)row * 2] = t0;  topi[(size_t)row * 2 + 1] = t1;
    }
  }
  if (l < 8) { atomicAdd(&imps[e], impAcc); atomicAdd(&cnt[e], cntAcc); }
}

__global__ void k_scan(const int* __restrict__ cnt, int* __restrict__ basep, int* __restrict__ curs) {
  if (threadIdx.x == 0) {
    int a = 0;
    for (int e = 0; e < 8; e++) { basep[e] = a; a += cnt[e]; }
  }
  if (threadIdx.x < 8) curs[threadIdx.x] = 0;
}

__global__ __launch_bounds__(256) void k_scatter(const int* __restrict__ topi, const int* __restrict__ basep,
    int* __restrict__ cursor, int* __restrict__ rowlist, int* __restrict__ rowpos)
{
  __shared__ int lcnt[8], lbase[8];
  const int t = threadIdx.x;
  if (t < 8) lcnt[t] = 0;
  __syncthreads();
  const int token = blockIdx.x * 256 + t;
  const int e0 = topi[token * 2], e1 = topi[token * 2 + 1];
  const int p0 = atomicAdd(&lcnt[e0], 1);
  const int p1 = atomicAdd(&lcnt[e1], 1);
  __syncthreads();
  if (t < 8) lbase[t] = atomicAdd(&cursor[t], lcnt[t]);
  __syncthreads();
  const int pos0 = basep[e0] + lbase[e0] + p0;
  const int pos1 = basep[e1] + lbase[e1] + p1;
  rowlist[pos0] = token; rowlist[pos1] = token;
  rowpos[token * 2] = pos0; rowpos[token * 2 + 1] = pos1;
}

__global__ void k_loss(const int* __restrict__ cnt, const float* __restrict__ imps,
                       float* __restrict__ lossws, float* __restrict__ out, int phase) {
  if (threadIdx.x == 0 && blockIdx.x == 0) {
    float s = 0.f;
    for (int e = 0; e < 8; e++) s += ((float)cnt[e]) * imps[e];
    s *= 8.f / (8192.f * 8192.f);
    if (phase == 0) *lossws = s;
    else out[0] = *lossws + s;
  }
}

// ---------------- expert GEMM1: H = gelu(gather(XN) @ W1[e] + b1[e]) (bf16 out) ----------------
__global__ __launch_bounds__(256) void k_moe_g1(const float* __restrict__ XNp, const float* __restrict__ W1,
    const float* __restrict__ B1, bf16* __restrict__ H,
    const int* __restrict__ rowlist, const int* __restrict__ basep, const int* __restrict__ cntp)
{
  const int e = blockIdx.z;
  const int cnt = cntp[e];
  const int m0 = blockIdx.y * 128;
  if (m0 >= cnt) return;
  const int base = basep[e];
  const int n0 = blockIdx.x * 128;
  const float* Bw = W1 + (size_t)e * 512 * 2048;
  const float* be = B1 + (size_t)e * 2048;
  __shared__ float As[16][132];
  __shared__ float Bs[16][132];
  __shared__ int rl[128];
  const int t = threadIdx.x;
  if (t < 128) rl[t] = rowlist[base + min(m0 + t, cnt - 1)];
  __syncthreads();
  const int tx = t & 15, ty = t >> 4;
  const int ar = t >> 1, ac = (t & 1) * 8;
  const int br = t >> 4, bc = (t & 15) * 8;
  float acc[8][8];
#pragma unroll
  for (int i = 0; i < 8; i++)
#pragma unroll
    for (int j = 0; j < 8; j++) acc[i][j] = 0.f;
  const float* arow = XNp + (size_t)rl[ar] * 512;
  for (int k0 = 0; k0 < 512; k0 += 16) {
    {
      const float* ap = arow + k0 + ac;
      float4 a0 = *(const float4*)ap;
      float4 a1 = *(const float4*)(ap + 4);
      As[ac+0][ar]=a0.x; As[ac+1][ar]=a0.y; As[ac+2][ar]=a0.z; As[ac+3][ar]=a0.w;
      As[ac+4][ar]=a1.x; As[ac+5][ar]=a1.y; As[ac+6][ar]=a1.z; As[ac+7][ar]=a1.w;
    }
    {
      const float* bp = Bw + (size_t)(k0 + br) * 2048 + (n0 + bc);
      float4 b0 = *(const float4*)bp;
      float4 b1 = *(const float4*)(bp + 4);
      Bs[br][bc+0]=b0.x; Bs[br][bc+1]=b0.y; Bs[br][bc+2]=b0.z; Bs[br][bc+3]=b0.w;
      Bs[br][bc+4]=b1.x; Bs[br][bc+5]=b1.y; Bs[br][bc+6]=b1.z; Bs[br][bc+7]=b1.w;
    }
    __syncthreads();
#pragma unroll
    for (int kk = 0; kk < 16; kk++) {
      float4 a0 = *(const float4*)&As[kk][ty*8];
      float4 a1 = *(const float4*)&As[kk][ty*8+4];
      float4 b0 = *(const float4*)&Bs[kk][tx*8];
      float4 b1 = *(const float4*)&Bs[kk][tx*8+4];
      float av[8] = {a0.x,a0.y,a0.z,a0.w,a1.x,a1.y,a1.z,a1.w};
      float bv[8] = {b0.x,b0.y,b0.z,b0.w,b1.x,b1.y,b1.z,b1.w};
#pragma unroll
      for (int i = 0; i < 8; i++)
#pragma unroll
        for (int j = 0; j < 8; j++) acc[i][j] = fmaf(av[i], bv[j], acc[i][j]);
    }
    __syncthreads();
  }
#pragma unroll
  for (int i = 0; i < 8; i++) {
    const int lr = ty * 8 + i;
    if (m0 + lr < cnt) {
      bf16* hp = H + (size_t)(base + m0 + lr) * 2048 + (n0 + tx * 8);
      union { bf16 h[8]; uint4 q; } pk;
#pragma unroll
      for (int j = 0; j < 8; j++) {
        float v = acc[i][j] + be[n0 + tx * 8 + j];
        float g = 0.5f * v * (1.f + erff(v * 0.70710678118654752f));
        pk.h[j] = f2b(g);
      }
      *(uint4*)hp = pk.q;
    }
  }
}

// ---------------- expert GEMM2: YB = H @ W2[e] + b2[e] (f32 out) ----------------
__global__ __launch_bounds__(256) void k_moe_g2(const bf16* __restrict__ H, const float* __restrict__ W2,
    const float* __restrict__ B2, float* __restrict__ YB,
    const int* __restrict__ basep, const int* __restrict__ cntp)
{
  const int e = blockIdx.z;
  const int cnt = cntp[e];
  const int m0 = blockIdx.y * 128;
  if (m0 >= cnt) return;
  const int base = basep[e];
  const int n0 = blockIdx.x * 128;
  const float* Bw = W2 + (size_t)e * 2048 * 512;
  const float* be = B2 + (size_t)e * 512;
  __shared__ float As[16][132];
  __shared__ float Bs[16][132];
  const int t = threadIdx.x;
  const int tx = t & 15, ty = t >> 4;
  const int ar = t >> 1, ac = (t & 1) * 8;
  const int br = t >> 4, bc = (t & 15) * 8;
  float acc[8][8];
#pragma unroll
  for (int i = 0; i < 8; i++)
#pragma unroll
    for (int j = 0; j < 8; j++) acc[i][j] = 0.f;
  const int grow = min(base + m0 + ar, 16383);
  const unsigned short* arow = (const unsigned short*)H + (size_t)grow * 2048;
  for (int k0 = 0; k0 < 2048; k0 += 16) {
    {
      uint4 u = *(const uint4*)(arow + k0 + ac);
      float fa[8]; unp8(u, fa);
#pragma unroll
      for (int i = 0; i < 8; i++) As[ac+i][ar] = fa[i];
    }
    {
      const float* bp = Bw + (size_t)(k0 + br) * 512 + (n0 + bc);
      float4 b0 = *(const float4*)bp;
      float4 b1 = *(const float4*)(bp + 4);
      Bs[br][bc+0]=b0.x; Bs[br][bc+1]=b0.y; Bs[br][bc+2]=b0.z; Bs[br][bc+3]=b0.w;
      Bs[br][bc+4]=b1.x; Bs[br][bc+5]=b1.y; Bs[br][bc+6]=b1.z; Bs[br][bc+7]=b1.w;
    }
    __syncthreads();
#pragma unroll
    for (int kk = 0; kk < 16; kk++) {
      float4 a0 = *(const float4*)&As[kk][ty*8];
      float4 a1 = *(const float4*)&As[kk][ty*8+4];
      float4 b0 = *(const float4*)&Bs[kk][tx*8];
      float4 b1 = *(const float4*)&Bs[kk][tx*8+4];
      float av[8] = {a0.x,a0.y,a0.z,a0.w,a1.x,a1.y,a1.z,a1.w};
      float bv[8] = {b0.x,b0.y,b0.z,b0.w,b1.x,b1.y,b1.z,b1.w};
#pragma unroll
      for (int i = 0; i < 8; i++)
#pragma unroll
        for (int j = 0; j < 8; j++) acc[i][j] = fmaf(av[i], bv[j], acc[i][j]);
    }
    __syncthreads();
  }
#pragma unroll
  for (int i = 0; i < 8; i++) {
    const int lr = ty * 8 + i;
    if (m0 + lr < cnt) {
      float* yp = YB + (size_t)(base + m0 + lr) * 512 + (n0 + tx * 8);
      float vals[8];
#pragma unroll
      for (int j = 0; j < 8; j++) vals[j] = acc[i][j] + be[n0 + tx * 8 + j];
      float4 s0 = {vals[0],vals[1],vals[2],vals[3]};
      float4 s1 = {vals[4],vals[5],vals[6],vals[7]};
      *(float4*)yp = s0; *(float4*)(yp + 4) = s1;
    }
  }
}

// ---------------- combine: out[token] = g0*YB[pos0] + g1*YB[pos1] ----------------
__global__ __launch_bounds__(256) void k_combine(const float* __restrict__ YB, const float* __restrict__ gates,
    const int* __restrict__ rowpos, float* __restrict__ OUT)
{
  const int idx = blockIdx.x * 256 + threadIdx.x;
  const int row = idx >> 9, d = idx & 511;
  const float g0 = gates[row * 2], g1 = gates[row * 2 + 1];
  const int r0 = rowpos[row * 2], r1 = rowpos[row * 2 + 1];
  OUT[idx] = g0 * YB[(size_t)r0 * 512 + d] + g1 * YB[(size_t)r1 * 512 + d];
}

// ---------------- fv = mean over S (writes ws copy + output) ----------------
__global__ __launch_bounds__(256) void k_fv(const float* __restrict__ O2, float* __restrict__ FVp, float* __restrict__ outv) {
  const int idx = blockIdx.x * 256 + threadIdx.x;  // 16384
  const int b = idx >> 9, d = idx & 511;
  const float* p = O2 + (size_t)b * 131072 + d;
  float s = 0.f;
  for (int i = 0; i < 256; i++) s += p[i * 512];
  s *= (1.f / 256.f);
  FVp[idx] = s;
  outv[idx] = s;
}

// ---------------- logits = fv @ cls_w + cls_b ----------------
__global__ __launch_bounds__(256) void k_cls(const float* __restrict__ FVp, const float* __restrict__ W,
    const float* __restrict__ bias, float* __restrict__ outl) {
  const int idx = blockIdx.x * 256 + threadIdx.x;  // 16384
  const int b = idx >> 9, n = idx & 511;
  const float* f = FVp + (size_t)b * 512;
  float s = 0.f;
  for (int d = 0; d < 512; d++) s = fmaf(f[d], W[(size_t)d * 512 + n], s);
  s += bias[n];
  outl[idx] = s;
}

extern "C" void kernel_launch(void* const* d_in, const int* in_sizes, int n_in,
                              void* d_out, int out_size, void* d_ws, size_t ws_size,
                              hipStream_t stream)
{
  (void)in_sizes; (void)n_in; (void)out_size; (void)ws_size;
  const float* x    = (const float*)d_in[0];
  const float* pe_w = (const float*)d_in[1];
  const float* pe_b = (const float*)d_in[2];
  const float* pos  = (const float*)d_in[3];
  const float* ln1g = (const float*)d_in[4];
  const float* ln1b = (const float*)d_in[5];
  const float* lng[2] = {(const float*)d_in[6], (const float*)d_in[8]};
  const float* lnb[2] = {(const float*)d_in[7], (const float*)d_in[9]};
  const float* wq = (const float*)d_in[10]; const float* bq = (const float*)d_in[11];
  const float* wk = (const float*)d_in[12]; const float* bk = (const float*)d_in[13];
  const float* wv = (const float*)d_in[14]; const float* bv = (const float*)d_in[15];
  const float* wo = (const float*)d_in[16]; const float* bo = (const float*)d_in[17];
  const float* m_rw[2] = {(const float*)d_in[18], (const float*)d_in[24]};
  const float* m_rb[2] = {(const float*)d_in[19], (const float*)d_in[25]};
  const float* m_w1[2] = {(const float*)d_in[20], (const float*)d_in[26]};
  const float* m_b1[2] = {(const float*)d_in[21], (const float*)d_in[27]};
  const float* m_w2[2] = {(const float*)d_in[22], (const float*)d_in[28]};
  const float* m_b2[2] = {(const float*)d_in[23], (const float*)d_in[29]};
  const float* cls_w = (const float*)d_in[30];
  const float* cls_b = (const float*)d_in[31];

  float* ws = (float*)d_ws;
  float* patches = ws + OF_PATCH;
  float* ebuf = ws + OF_E;
  float* xn   = ws + OF_XN;
  float* qb   = ws + OF_Q;
  float* kb   = ws + OF_K;
  float* vb   = ws + OF_V;
  float* ctx  = ws + OF_CTX;
  float* o1   = ws + OF_O1;
  float* o2   = ws + OF_O2;
  float* fv   = ws + OF_FV;
  float* gates = ws + OF_GATES;
  float* imps  = ws + OF_IMPS;
  int* cnt    = (int*)(ws + OF_CNT);
  int* basep  = (int*)(ws + OF_BASE);
  int* curs   = (int*)(ws + OF_CURS);
  float* lossws = ws + OF_LOSS;
  int* topi   = (int*)(ws + OF_TOPI);
  int* rowpos = (int*)(ws + OF_RPOS);
  int* rowlist= (int*)(ws + OF_RLIST);
  bf16* Hbuf  = (bf16*)(ws + OF_Q);   // overlay on q/k/v/ctx (dead after wo-GEMM)
  float* YB   = ws + OF_PATCH;        // overlay on patches+e (dead after LN2)

  float* out = (float*)d_out;
  float* out_logits = out;
  float* out_fv     = out + 16384;
  float* out_loss   = out + 32768;
  float* out_attnw  = out + 32769;

  k_patchify<<<18816, 256, 0, stream>>>(x, patches);
  k_gemm<0><<<dim3(4, 64), 256, 0, stream>>>(patches, pe_w, ebuf, 8192, 512, 588, pe_b, pos);
  k_ln<<<8192, 256, 0, stream>>>(ebuf, xn, ln1g, ln1b);
  k_gemm<1><<<dim3(4, 64), 256, 0, stream>>>(xn, wq, qb, 8192, 512, 512, bq, nullptr);
  k_gemm<1><<<dim3(4, 64), 256, 0, stream>>>(xn, wk, kb, 8192, 512, 512, bk, nullptr);
  k_gemm<1><<<dim3(4, 64), 256, 0, stream>>>(xn, wv, vb, 8192, 512, 512, bv, nullptr);
  k_attn<<<dim3(16, 32), 256, 0, stream>>>(qb, kb, vb, ctx, out_attnw);
  k_gemm<2><<<dim3(4, 64), 256, 0, stream>>>(ctx, wo, ebuf, 8192, 512, 512, bo, nullptr);  // e += ctx@wo + bo

  const float* moe_in[2] = {ebuf, o1};
  float* moe_out[2] = {o1, o2};
  for (int mi = 0; mi < 2; mi++) {
    hipMemsetAsync(imps, 0, 64, stream);   // zero imps(32B) + cnt(32B)
    k_ln<<<8192, 256, 0, stream>>>(moe_in[mi], xn, lng[mi], lnb[mi]);
    k_router<<<32, 256, 0, stream>>>(xn, m_rw[mi], m_rb[mi], gates, topi, cnt, imps);
    k_scan<<<1, 64, 0, stream>>>(cnt, basep, curs);
    k_scatter<<<32, 256, 0, stream>>>(topi, basep, curs, rowlist, rowpos);
    k_loss<<<1, 64, 0, stream>>>(cnt, imps, lossws, out_loss, mi);
    k_moe_g1<<<dim3(16, 64, 8), 256, 0, stream>>>(xn, m_w1[mi], m_b1[mi], Hbuf, rowlist, basep, cnt);
    k_moe_g2<<<dim3(4, 64, 8), 256, 0, stream>>>(Hbuf, m_w2[mi], m_b2[mi], YB, basep, cnt);
    k_combine<<<16384, 256, 0, stream>>>(YB, gates, rowpos, moe_out[mi]);
  }
  k_fv<<<64, 256, 0, stream>>>(o2, fv, out_fv);
  k_cls<<<64, 256, 0, stream>>>(fv, cls_w, cls_b, out_logits);
}

// Round 3
// 1759.203 us; speedup vs baseline: 2.0049x; 2.0049x over previous
//
#include <hip/hip_runtime.h>
#include <hip/hip_bf16.h>

using bf16 = __hip_bfloat16;
typedef unsigned short u16;
typedef __attribute__((ext_vector_type(8))) short short8;
typedef __attribute__((ext_vector_type(4))) float f32x4;

#define DEVFN __device__ __forceinline__

DEVFN u16 f2bu(float v) { return __builtin_bit_cast(u16, __float2bfloat16(v)); }

DEVFN f32x4 mfma16(short8 a, short8 b, f32x4 c) {
  return __builtin_amdgcn_mfma_f32_16x16x32_bf16(a, b, c, 0, 0, 0);
}

// ---------------- workspace layout (float element offsets) ----------------
// total: 38,453,288 floats = ~147 MiB (same footprint as the passing round)
static constexpr size_t OF_PATCH = 0;          // 8192*588 f32
static constexpr size_t OF_E     = 4816896;    // 8192*512
static constexpr size_t OF_XN    = 9011200;    // 8192*512
static constexpr size_t OF_Q     = 13205504;   // 8192*512
static constexpr size_t OF_K     = 17399808;
static constexpr size_t OF_V     = 21594112;
static constexpr size_t OF_CTX   = 25788416;
static constexpr size_t OF_O1    = 29982720;
static constexpr size_t OF_O2    = 34177024;
static constexpr size_t OF_FV    = 38371328;   // 32*512
static constexpr size_t OF_GATES = 38387712;   // 8192*2
static constexpr size_t OF_IMPS  = 38404096;   // 8 f32  (memset with CNT: 64B)
static constexpr size_t OF_CNT   = 38404104;   // 8 i32
static constexpr size_t OF_BASE  = 38404112;   // 8 i32
static constexpr size_t OF_CURS  = 38404120;   // 8 i32
static constexpr size_t OF_LOSS  = 38404128;   // 1 f32 (+pad)
static constexpr size_t OF_TOPI  = 38404136;   // 8192*2 i32
static constexpr size_t OF_RPOS  = 38420520;   // 8192*2 i32
static constexpr size_t OF_RLIST = 38436904;   // 16384 i32
// Overlays (all lifetime-checked):
//  H   (bf16 16384x2048) on [OF_Q, OF_O1)            — q/k/v/ctx dead during MoE
//  YB  (f32 16384x512)   on [0, 8388608)             — patches+ebuf dead by g2
//  XNB (bf16 8192x512)   on [0, 2097152) f-units     — dead before YB written
//  W1T (bf16 8x2048x512) on [OF_O1, OF_O1+4194304)   — o1 written only at combine (after g1 done)
//  W2T (bf16 8x512x2048) on [OF_O2, OF_O2+4194304)   — o2 written only at layer-2 combine (after g2 done)

// ---------------- patchify: x[B,3,224,224] -> patches[8192,588] ----------------
__global__ __launch_bounds__(256) void k_patchify(const float* __restrict__ x, float* __restrict__ patches) {
  int idx = blockIdx.x * 256 + threadIdx.x;
  if (idx >= 8192 * 588) return;
  int row = idx / 588, j = idx - row * 588;
  int b = row >> 8, s = row & 255;
  int hh = s >> 4, ww = s & 15;
  int c = j % 3, tt = j / 3;
  int p2 = tt % 14, p1 = tt / 14;
  int src = ((b * 3 + c) * 224 + hh * 14 + p1) * 224 + (ww * 14 + p2);
  patches[idx] = x[src];
}

// ---------------- generic tiled GEMM (fp32 vector): C = A @ B ----------------
// EPI 0: + bias + pos ; EPI 1: + bias ; EPI 2: + bias, accumulate into C
template<int EPI>
__global__ __launch_bounds__(256) void k_gemm(const float* __restrict__ A, const float* __restrict__ Bw,
    float* __restrict__ C, int M, int N, int K,
    const float* __restrict__ bias, const float* __restrict__ pos)
{
  __shared__ float As[16][132];
  __shared__ float Bs[16][132];
  const int t = threadIdx.x;
  const int m0 = blockIdx.y * 128, n0 = blockIdx.x * 128;
  const int tx = t & 15, ty = t >> 4;
  const int ar = t >> 1, ac = (t & 1) * 8;
  const int br = t >> 4, bc = (t & 15) * 8;
  float acc[8][8];
#pragma unroll
  for (int i = 0; i < 8; i++)
#pragma unroll
    for (int j = 0; j < 8; j++) acc[i][j] = 0.f;

  for (int k0 = 0; k0 < K; k0 += 16) {
    if (k0 + ac + 8 <= K) {
      const float* ap = A + (size_t)(m0 + ar) * K + (k0 + ac);
      float4 a0 = *(const float4*)ap;
      float4 a1 = *(const float4*)(ap + 4);
      As[ac+0][ar]=a0.x; As[ac+1][ar]=a0.y; As[ac+2][ar]=a0.z; As[ac+3][ar]=a0.w;
      As[ac+4][ar]=a1.x; As[ac+5][ar]=a1.y; As[ac+6][ar]=a1.z; As[ac+7][ar]=a1.w;
    } else {
      const float* ap = A + (size_t)(m0 + ar) * K;
#pragma unroll
      for (int i = 0; i < 8; i++) { int kk = k0 + ac + i; As[ac+i][ar] = (kk < K) ? ap[kk] : 0.f; }
    }
    {
      int kk = k0 + br;
      if (kk < K) {
        const float* bp = Bw + (size_t)kk * N + (n0 + bc);
        float4 b0 = *(const float4*)bp;
        float4 b1 = *(const float4*)(bp + 4);
        Bs[br][bc+0]=b0.x; Bs[br][bc+1]=b0.y; Bs[br][bc+2]=b0.z; Bs[br][bc+3]=b0.w;
        Bs[br][bc+4]=b1.x; Bs[br][bc+5]=b1.y; Bs[br][bc+6]=b1.z; Bs[br][bc+7]=b1.w;
      } else {
#pragma unroll
        for (int i = 0; i < 8; i++) Bs[br][bc+i] = 0.f;
      }
    }
    __syncthreads();
#pragma unroll
    for (int kk = 0; kk < 16; kk++) {
      float4 a0 = *(const float4*)&As[kk][ty*8];
      float4 a1 = *(const float4*)&As[kk][ty*8+4];
      float4 b0 = *(const float4*)&Bs[kk][tx*8];
      float4 b1 = *(const float4*)&Bs[kk][tx*8+4];
      float av[8] = {a0.x,a0.y,a0.z,a0.w,a1.x,a1.y,a1.z,a1.w};
      float bv[8] = {b0.x,b0.y,b0.z,b0.w,b1.x,b1.y,b1.z,b1.w};
#pragma unroll
      for (int i = 0; i < 8; i++)
#pragma unroll
        for (int j = 0; j < 8; j++) acc[i][j] = fmaf(av[i], bv[j], acc[i][j]);
    }
    __syncthreads();
  }
#pragma unroll
  for (int i = 0; i < 8; i++) {
    int m = m0 + ty * 8 + i;
    float* cp = C + (size_t)m * N + (n0 + tx * 8);
    float vals[8];
#pragma unroll
    for (int j = 0; j < 8; j++) {
      int n = n0 + tx * 8 + j;
      float v = acc[i][j] + bias[n];
      if (EPI == 0) v += pos[(size_t)(m & 255) * 512 + n];
      vals[j] = v;
    }
    if (EPI == 2) {
      float4 o0 = *(const float4*)cp;
      float4 o1 = *(const float4*)(cp + 4);
      vals[0]+=o0.x; vals[1]+=o0.y; vals[2]+=o0.z; vals[3]+=o0.w;
      vals[4]+=o1.x; vals[5]+=o1.y; vals[6]+=o1.z; vals[7]+=o1.w;
    }
    float4 s0 = {vals[0],vals[1],vals[2],vals[3]};
    float4 s1 = {vals[4],vals[5],vals[6],vals[7]};
    *(float4*)cp = s0; *(float4*)(cp + 4) = s1;
  }
}

// ---------------- LayerNorm over D=512 (writes f32 + bf16 copies) ----------------
__global__ __launch_bounds__(256) void k_ln(const float* __restrict__ X, float* __restrict__ Y,
    u16* __restrict__ YB16, const float* __restrict__ g, const float* __restrict__ b)
{
  __shared__ float red[256];
  const int row = blockIdx.x;
  const int t = threadIdx.x;
  const float* xr = X + (size_t)row * 512;
  float x0 = xr[t], x1 = xr[t + 256];
  red[t] = x0 + x1;
  __syncthreads();
  for (int s = 128; s > 0; s >>= 1) { if (t < s) red[t] += red[t + s]; __syncthreads(); }
  float mean = red[0] * (1.f / 512.f);
  __syncthreads();
  float d0 = x0 - mean, d1 = x1 - mean;
  red[t] = d0 * d0 + d1 * d1;
  __syncthreads();
  for (int s = 128; s > 0; s >>= 1) { if (t < s) red[t] += red[t + s]; __syncthreads(); }
  float rs = 1.f / sqrtf(red[0] * (1.f / 512.f) + 1e-5f);
  float y0 = d0 * rs * g[t]       + b[t];
  float y1 = d1 * rs * g[t + 256] + b[t + 256];
  float* yr = Y + (size_t)row * 512;
  yr[t] = y0; yr[t + 256] = y1;
  u16* br16 = YB16 + (size_t)row * 512;
  br16[t] = f2bu(y0); br16[t + 256] = f2bu(y1);
}

// ---------------- attention (fp32, unchanged from passing round) ----------------
__global__ __launch_bounds__(256) void k_attn(const float* __restrict__ Q, const float* __restrict__ Kb,
    const float* __restrict__ V, float* __restrict__ CTXp, float* __restrict__ AW)
{
  __shared__ float qs[16][65];
  __shared__ float kt[64][65];
  __shared__ float Sm[16][257];
  __shared__ float ab[16][257];
  const int t = threadIdx.x;
  const int b = blockIdx.y, qt = blockIdx.x;
  const int qi0 = qt * 16;
  for (int i = t; i < 4096; i += 256) ab[i >> 8][i & 255] = 0.f;

  const int sr = t >> 4, sc4 = (t & 15) * 4;
  const size_t qbase = (size_t)(b * 256 + qi0) * 512;

  for (int h = 0; h < 8; h++) {
    {
      float4 qv = *(const float4*)(Q + qbase + (size_t)sr * 512 + h * 64 + sc4);
      qs[sr][sc4]=qv.x; qs[sr][sc4+1]=qv.y; qs[sr][sc4+2]=qv.z; qs[sr][sc4+3]=qv.w;
    }
    for (int kc = 0; kc < 4; kc++) {
      __syncthreads();
#pragma unroll
      for (int i = 0; i < 4; i++) {
        int rr = sr + i * 16;
        float4 kv = *(const float4*)(Kb + (size_t)(b * 256 + kc * 64 + rr) * 512 + h * 64 + sc4);
        kt[rr][sc4]=kv.x; kt[rr][sc4+1]=kv.y; kt[rr][sc4+2]=kv.z; kt[rr][sc4+3]=kv.w;
      }
      __syncthreads();
      const int q_l = t & 15, kg = t >> 4;
#pragma unroll
      for (int j = 0; j < 4; j++) {
        int k_l = kg * 4 + j;
        float s = 0.f;
#pragma unroll
        for (int d = 0; d < 64; d++) s = fmaf(qs[q_l][d], kt[k_l][d], s);
        Sm[q_l][kc * 64 + k_l] = s * 0.125f;
      }
    }
    __syncthreads();
    {
      const int row = t >> 4, seg = t & 15;
      float vals[16];
      float vmax = -1e30f;
#pragma unroll
      for (int i = 0; i < 16; i++) { vals[i] = Sm[row][seg * 16 + i]; vmax = fmaxf(vmax, vals[i]); }
#pragma unroll
      for (int mk = 1; mk < 16; mk <<= 1) vmax = fmaxf(vmax, __shfl_xor(vmax, mk, 64));
      float ssum = 0.f;
#pragma unroll
      for (int i = 0; i < 16; i++) { vals[i] = __expf(vals[i] - vmax); ssum += vals[i]; }
#pragma unroll
      for (int mk = 1; mk < 16; mk <<= 1) ssum += __shfl_xor(ssum, mk, 64);
      float inv = 1.f / ssum;
#pragma unroll
      for (int i = 0; i < 16; i++) {
        float p = vals[i] * inv;
        Sm[row][seg * 16 + i] = p;
        ab[row][seg * 16 + i] += 0.125f * p;
      }
    }
    float acc0 = 0.f, acc1 = 0.f, acc2 = 0.f, acc3 = 0.f;
    const int d = t & 63, qg = t >> 6;
    for (int vc = 0; vc < 4; vc++) {
      __syncthreads();
#pragma unroll
      for (int i = 0; i < 4; i++) {
        int rr = sr + i * 16;
        float4 vv = *(const float4*)(V + (size_t)(b * 256 + vc * 64 + rr) * 512 + h * 64 + sc4);
        kt[rr][sc4]=vv.x; kt[rr][sc4+1]=vv.y; kt[rr][sc4+2]=vv.z; kt[rr][sc4+3]=vv.w;
      }
      __syncthreads();
#pragma unroll
      for (int kk = 0; kk < 64; kk++) {
        float vv = kt[kk][d];
        acc0 = fmaf(Sm[qg    ][vc * 64 + kk], vv, acc0);
        acc1 = fmaf(Sm[qg + 4][vc * 64 + kk], vv, acc1);
        acc2 = fmaf(Sm[qg + 8][vc * 64 + kk], vv, acc2);
        acc3 = fmaf(Sm[qg +12][vc * 64 + kk], vv, acc3);
      }
    }
    {
      float* cb = CTXp + qbase + (size_t)h * 64 + d;
      cb[(size_t)(qg    ) * 512] = acc0;
      cb[(size_t)(qg + 4) * 512] = acc1;
      cb[(size_t)(qg + 8) * 512] = acc2;
      cb[(size_t)(qg +12) * 512] = acc3;
    }
  }
  __syncthreads();
  {
    const int row = t >> 4, seg = t & 15;
    float vals[16]; float vmax = -1e30f;
#pragma unroll
    for (int i = 0; i < 16; i++) { vals[i] = ab[row][seg * 16 + i]; vmax = fmaxf(vmax, vals[i]); }
#pragma unroll
    for (int mk = 1; mk < 16; mk <<= 1) vmax = fmaxf(vmax, __shfl_xor(vmax, mk, 64));
    float ssum = 0.f;
#pragma unroll
    for (int i = 0; i < 16; i++) { vals[i] = __expf(vals[i] - vmax); ssum += vals[i]; }
#pragma unroll
    for (int mk = 1; mk < 16; mk <<= 1) ssum += __shfl_xor(ssum, mk, 64);
    float inv = 1.f / ssum;
    float* orow = AW + (size_t)(b * 256 + qi0 + row) * 256 + seg * 16;
#pragma unroll
    for (int i = 0; i < 16; i++) orow[i] = vals[i] * inv;
  }
}

// ---------------- router (fp32, unchanged) ----------------
DEVFN int rwidx(int k, int e) { return k * 8 + e + (k >> 6) * 4; }

__global__ __launch_bounds__(256) void k_router(const float* __restrict__ XNp, const float* __restrict__ rw,
    const float* __restrict__ rb, float* __restrict__ gates, int* __restrict__ topi,
    int* __restrict__ cnt, float* __restrict__ imps)
{
  __shared__ float rws[4128];
  const int t = threadIdx.x;
  for (int i = t; i < 4096; i += 256) rws[rwidx(i >> 3, i & 7)] = rw[i];
  __syncthreads();
  const int w = t >> 6, l = t & 63;
  const int e = l & 7, ch = l >> 3;
  float impAcc = 0.f; int cntAcc = 0;
  const int row0 = blockIdx.x * 256 + w * 64;
  for (int r = 0; r < 64; r++) {
    const int row = row0 + r;
    const float* xr = XNp + (size_t)row * 512 + ch * 64;
    float s = 0.f;
#pragma unroll 8
    for (int j = 0; j < 64; j++) s = fmaf(xr[j], rws[rwidx(ch * 64 + j, e)], s);
    s += __shfl_xor(s, 8, 64);
    s += __shfl_xor(s, 16, 64);
    s += __shfl_xor(s, 32, 64);
    s += rb[e];
    float p[8];
#pragma unroll
    for (int i = 0; i < 8; i++) p[i] = __shfl(s, (l & 56) | i, 64);
    float mx = p[0];
#pragma unroll
    for (int i = 1; i < 8; i++) mx = fmaxf(mx, p[i]);
    float sum = 0.f;
#pragma unroll
    for (int i = 0; i < 8; i++) { p[i] = __expf(p[i] - mx); sum += p[i]; }
    float inv = 1.f / sum;
#pragma unroll
    for (int i = 0; i < 8; i++) p[i] *= inv;
    int t0 = 0; float v0 = p[0];
#pragma unroll
    for (int i = 1; i < 8; i++) if (p[i] > v0) { v0 = p[i]; t0 = i; }
    int t1 = -1; float v1 = -1.f;
#pragma unroll
    for (int i = 0; i < 8; i++) if (i != t0 && p[i] > v1) { v1 = p[i]; t1 = i; }
    if (l < 8) { impAcc += p[e]; cntAcc += (t0 == e) + (t1 == e); }
    if (l == 0) {
      gates[(size_t)row * 2] = v0; gates[(size_t)row * 2 + 1] = v1;
      topi[(size_t)row * 2] = t0;  topi[(size_t)row * 2 + 1] = t1;
    }
  }
  if (l < 8) { atomicAdd(&imps[e], impAcc); atomicAdd(&cnt[e], cntAcc); }
}

__global__ void k_scan(const int* __restrict__ cnt, int* __restrict__ basep, int* __restrict__ curs) {
  if (threadIdx.x == 0) {
    int a = 0;
    for (int e = 0; e < 8; e++) { basep[e] = a; a += cnt[e]; }
  }
  if (threadIdx.x < 8) curs[threadIdx.x] = 0;
}

__global__ __launch_bounds__(256) void k_scatter(const int* __restrict__ topi, const int* __restrict__ basep,
    int* __restrict__ cursor, int* __restrict__ rowlist, int* __restrict__ rowpos)
{
  __shared__ int lcnt[8], lbase[8];
  const int t = threadIdx.x;
  if (t < 8) lcnt[t] = 0;
  __syncthreads();
  const int token = blockIdx.x * 256 + t;
  const int e0 = topi[token * 2], e1 = topi[token * 2 + 1];
  const int p0 = atomicAdd(&lcnt[e0], 1);
  const int p1 = atomicAdd(&lcnt[e1], 1);
  __syncthreads();
  if (t < 8) lbase[t] = atomicAdd(&cursor[t], lcnt[t]);
  __syncthreads();
  const int pos0 = basep[e0] + lbase[e0] + p0;
  const int pos1 = basep[e1] + lbase[e1] + p1;
  rowlist[pos0] = token; rowlist[pos1] = token;
  rowpos[token * 2] = pos0; rowpos[token * 2 + 1] = pos1;
}

__global__ void k_loss(const int* __restrict__ cnt, const float* __restrict__ imps,
                       float* __restrict__ lossws, float* __restrict__ out, int phase) {
  if (threadIdx.x == 0 && blockIdx.x == 0) {
    float s = 0.f;
    for (int e = 0; e < 8; e++) s += ((float)cnt[e]) * imps[e];
    s *= 8.f / (8192.f * 8192.f);
    if (phase == 0) *lossws = s;
    else out[0] = *lossws + s;
  }
}

// ---------------- weight convert+transpose: W[K,N] f32 -> Wt[N,K] bf16 (per expert) ----------------
__global__ __launch_bounds__(256) void k_wcvt(const float* __restrict__ W, u16* __restrict__ Wt, int K, int N)
{
  __shared__ float s[32][33];
  const int t = threadIdx.x;
  const int tx = t & 31, ty = t >> 5;
  const int k0 = blockIdx.x * 32, n0 = blockIdx.y * 32;
  const size_t es = (size_t)K * N;
  const float* We = W + (size_t)blockIdx.z * es;
  u16* Wte = Wt + (size_t)blockIdx.z * es;
#pragma unroll
  for (int i = 0; i < 4; i++) s[ty + i * 8][tx] = We[(size_t)(k0 + ty + i * 8) * N + n0 + tx];
  __syncthreads();
#pragma unroll
  for (int i = 0; i < 4; i++) Wte[(size_t)(n0 + ty + i * 8) * K + k0 + tx] = f2bu(s[tx][ty + i * 8]);
}

// ---------------- MFMA expert GEMM1: H = gelu(gather(XNB) @ W1[e] + b1[e]) bf16 out ----------------
// 128x128 tile, BK=32, mfma_f32_16x16x32_bf16; LDS row stride 40 (padding -> conflict-free b128)
__global__ __launch_bounds__(256) void k_mg1(const u16* __restrict__ XNB, const u16* __restrict__ W1T,
    const float* __restrict__ B1, u16* __restrict__ H,
    const int* __restrict__ rowlist, const int* __restrict__ basep, const int* __restrict__ cntp)
{
  const int e = blockIdx.z;
  const int cnt = cntp[e];
  const int m0 = blockIdx.y * 128;
  if (m0 >= cnt) return;
  const int base = basep[e];
  const int n0 = blockIdx.x * 128;
  __shared__ u16 As[128 * 40];
  __shared__ u16 Bs[128 * 40];
  __shared__ int rl[128];
  const int t = threadIdx.x;
  if (t < 128) rl[t] = rowlist[base + min(m0 + t, cnt - 1)];
  __syncthreads();
  const int r0 = t >> 2, c0 = (t & 3) * 8;
  const u16* pa0 = XNB + (size_t)rl[r0] * 512 + c0;
  const u16* pa1 = XNB + (size_t)rl[r0 + 64] * 512 + c0;
  const u16* wt = W1T + (size_t)e * (2048 * 512);
  const u16* pb0 = wt + (size_t)(n0 + r0) * 512 + c0;
  const u16* pb1 = wt + (size_t)(n0 + r0 + 64) * 512 + c0;
  u16* sa0 = &As[r0 * 40 + c0]; u16* sa1 = &As[(r0 + 64) * 40 + c0];
  u16* sb0 = &Bs[r0 * 40 + c0]; u16* sb1 = &Bs[(r0 + 64) * 40 + c0];
  const int lane = t & 63, wv = t >> 6;
  const int wm = (wv & 1) * 64, wn = (wv >> 1) * 64;
  const int ml = lane & 15, kq = lane >> 4;
  f32x4 acc[4][4];
#pragma unroll
  for (int i = 0; i < 4; i++)
#pragma unroll
    for (int j = 0; j < 4; j++) acc[i][j] = (f32x4){0.f, 0.f, 0.f, 0.f};
  for (int k0 = 0; k0 < 512; k0 += 32) {
    uint4 ga0 = *(const uint4*)(pa0 + k0);
    uint4 ga1 = *(const uint4*)(pa1 + k0);
    uint4 gb0 = *(const uint4*)(pb0 + k0);
    uint4 gb1 = *(const uint4*)(pb1 + k0);
    __syncthreads();
    *(uint4*)sa0 = ga0; *(uint4*)sa1 = ga1;
    *(uint4*)sb0 = gb0; *(uint4*)sb1 = gb1;
    __syncthreads();
    short8 af[4], bf[4];
#pragma unroll
    for (int i = 0; i < 4; i++) af[i] = *(const short8*)&As[(wm + i * 16 + ml) * 40 + kq * 8];
#pragma unroll
    for (int j = 0; j < 4; j++) bf[j] = *(const short8*)&Bs[(wn + j * 16 + ml) * 40 + kq * 8];
#pragma unroll
    for (int i = 0; i < 4; i++)
#pragma unroll
      for (int j = 0; j < 4; j++) acc[i][j] = mfma16(af[i], bf[j], acc[i][j]);
  }
#pragma unroll
  for (int j = 0; j < 4; j++) {
    const int n = n0 + wn + j * 16 + ml;
    const float bv = B1[e * 2048 + n];
#pragma unroll
    for (int i = 0; i < 4; i++) {
#pragma unroll
      for (int r = 0; r < 4; r++) {
        const int lr = wm + i * 16 + kq * 4 + r;
        if (m0 + lr < cnt) {
          float v = acc[i][j][r] + bv;
          float g = 0.5f * v * (1.f + erff(v * 0.70710678118654752f));
          H[(size_t)(base + m0 + lr) * 2048 + n] = f2bu(g);
        }
      }
    }
  }
}

// ---------------- MFMA expert GEMM2: YB = H @ W2[e] + b2[e] (f32 out) ----------------
__global__ __launch_bounds__(256) void k_mg2(const u16* __restrict__ H, const u16* __restrict__ W2T,
    const float* __restrict__ B2, float* __restrict__ YB,
    const int* __restrict__ basep, const int* __restrict__ cntp)
{
  const int e = blockIdx.z;
  const int cnt = cntp[e];
  const int m0 = blockIdx.y * 128;
  if (m0 >= cnt) return;
  const int base = basep[e];
  const int n0 = blockIdx.x * 128;
  __shared__ u16 As[128 * 40];
  __shared__ u16 Bs[128 * 40];
  const int t = threadIdx.x;
  const int r0 = t >> 2, c0 = (t & 3) * 8;
  const int gr0 = min(base + m0 + r0, 16383);
  const int gr1 = min(base + m0 + r0 + 64, 16383);
  const u16* pa0 = H + (size_t)gr0 * 2048 + c0;
  const u16* pa1 = H + (size_t)gr1 * 2048 + c0;
  const u16* wt = W2T + (size_t)e * (512 * 2048);
  const u16* pb0 = wt + (size_t)(n0 + r0) * 2048 + c0;
  const u16* pb1 = wt + (size_t)(n0 + r0 + 64) * 2048 + c0;
  u16* sa0 = &As[r0 * 40 + c0]; u16* sa1 = &As[(r0 + 64) * 40 + c0];
  u16* sb0 = &Bs[r0 * 40 + c0]; u16* sb1 = &Bs[(r0 + 64) * 40 + c0];
  const int lane = t & 63, wv = t >> 6;
  const int wm = (wv & 1) * 64, wn = (wv >> 1) * 64;
  const int ml = lane & 15, kq = lane >> 4;
  f32x4 acc[4][4];
#pragma unroll
  for (int i = 0; i < 4; i++)
#pragma unroll
    for (int j = 0; j < 4; j++) acc[i][j] = (f32x4){0.f, 0.f, 0.f, 0.f};
  for (int k0 = 0; k0 < 2048; k0 += 32) {
    uint4 ga0 = *(const uint4*)(pa0 + k0);
    uint4 ga1 = *(const uint4*)(pa1 + k0);
    uint4 gb0 = *(const uint4*)(pb0 + k0);
    uint4 gb1 = *(const uint4*)(pb1 + k0);
    __syncthreads();
    *(uint4*)sa0 = ga0; *(uint4*)sa1 = ga1;
    *(uint4*)sb0 = gb0; *(uint4*)sb1 = gb1;
    __syncthreads();
    short8 af[4], bf[4];
#pragma unroll
    for (int i = 0; i < 4; i++) af[i] = *(const short8*)&As[(wm + i * 16 + ml) * 40 + kq * 8];
#pragma unroll
    for (int j = 0; j < 4; j++) bf[j] = *(const short8*)&Bs[(wn + j * 16 + ml) * 40 + kq * 8];
#pragma unroll
    for (int i = 0; i < 4; i++)
#pragma unroll
      for (int j = 0; j < 4; j++) acc[i][j] = mfma16(af[i], bf[j], acc[i][j]);
  }
#pragma unroll
  for (int j = 0; j < 4; j++) {
    const int n = n0 + wn + j * 16 + ml;
    const float bv = B2[e * 512 + n];
#pragma unroll
    for (int i = 0; i < 4; i++) {
#pragma unroll
      for (int r = 0; r < 4; r++) {
        const int lr = wm + i * 16 + kq * 4 + r;
        if (m0 + lr < cnt)
          YB[(size_t)(base + m0 + lr) * 512 + n] = acc[i][j][r] + bv;
      }
    }
  }
}

// ---------------- combine / fv / cls (unchanged) ----------------
__global__ __launch_bounds__(256) void k_combine(const float* __restrict__ YB, const float* __restrict__ gates,
    const int* __restrict__ rowpos, float* __restrict__ OUT)
{
  const int idx = blockIdx.x * 256 + threadIdx.x;
  const int row = idx >> 9, d = idx & 511;
  const float g0 = gates[row * 2], g1 = gates[row * 2 + 1];
  const int r0 = rowpos[row * 2], r1 = rowpos[row * 2 + 1];
  OUT[idx] = g0 * YB[(size_t)r0 * 512 + d] + g1 * YB[(size_t)r1 * 512 + d];
}

__global__ __launch_bounds__(256) void k_fv(const float* __restrict__ O2, float* __restrict__ FVp, float* __restrict__ outv) {
  const int idx = blockIdx.x * 256 + threadIdx.x;  // 16384
  const int b = idx >> 9, d = idx & 511;
  const float* p = O2 + (size_t)b * 131072 + d;
  float s = 0.f;
  for (int i = 0; i < 256; i++) s += p[i * 512];
  s *= (1.f / 256.f);
  FVp[idx] = s;
  outv[idx] = s;
}

__global__ __launch_bounds__(256) void k_cls(const float* __restrict__ FVp, const float* __restrict__ W,
    const float* __restrict__ bias, float* __restrict__ outl) {
  const int idx = blockIdx.x * 256 + threadIdx.x;  // 16384
  const int b = idx >> 9, n = idx & 511;
  const float* f = FVp + (size_t)b * 512;
  float s = 0.f;
  for (int d = 0; d < 512; d++) s = fmaf(f[d], W[(size_t)d * 512 + n], s);
  s += bias[n];
  outl[idx] = s;
}

extern "C" void kernel_launch(void* const* d_in, const int* in_sizes, int n_in,
                              void* d_out, int out_size, void* d_ws, size_t ws_size,
                              hipStream_t stream)
{
  (void)in_sizes; (void)n_in; (void)out_size; (void)ws_size;
  const float* x    = (const float*)d_in[0];
  const float* pe_w = (const float*)d_in[1];
  const float* pe_b = (const float*)d_in[2];
  const float* pos  = (const float*)d_in[3];
  const float* ln1g = (const float*)d_in[4];
  const float* ln1b = (const float*)d_in[5];
  const float* lng[2] = {(const float*)d_in[6], (const float*)d_in[8]};
  const float* lnb[2] = {(const float*)d_in[7], (const float*)d_in[9]};
  const float* wq = (const float*)d_in[10]; const float* bq = (const float*)d_in[11];
  const float* wk = (const float*)d_in[12]; const float* bk = (const float*)d_in[13];
  const float* wv = (const float*)d_in[14]; const float* bv = (const float*)d_in[15];
  const float* wo = (const float*)d_in[16]; const float* bo = (const float*)d_in[17];
  const float* m_rw[2] = {(const float*)d_in[18], (const float*)d_in[24]};
  const float* m_rb[2] = {(const float*)d_in[19], (const float*)d_in[25]};
  const float* m_w1[2] = {(const float*)d_in[20], (const float*)d_in[26]};
  const float* m_b1[2] = {(const float*)d_in[21], (const float*)d_in[27]};
  const float* m_w2[2] = {(const float*)d_in[22], (const float*)d_in[28]};
  const float* m_b2[2] = {(const float*)d_in[23], (const float*)d_in[29]};
  const float* cls_w = (const float*)d_in[30];
  const float* cls_b = (const float*)d_in[31];

  float* ws = (float*)d_ws;
  float* patches = ws + OF_PATCH;
  float* ebuf = ws + OF_E;
  float* xn   = ws + OF_XN;
  float* qb   = ws + OF_Q;
  float* kb   = ws + OF_K;
  float* vb   = ws + OF_V;
  float* ctx  = ws + OF_CTX;
  float* o1   = ws + OF_O1;
  float* o2   = ws + OF_O2;
  float* fv   = ws + OF_FV;
  float* gates = ws + OF_GATES;
  float* imps  = ws + OF_IMPS;
  int* cnt    = (int*)(ws + OF_CNT);
  int* basep  = (int*)(ws + OF_BASE);
  int* curs   = (int*)(ws + OF_CURS);
  float* lossws = ws + OF_LOSS;
  int* topi   = (int*)(ws + OF_TOPI);
  int* rowpos = (int*)(ws + OF_RPOS);
  int* rowlist= (int*)(ws + OF_RLIST);
  u16* Hbuf  = (u16*)(ws + OF_Q);    // overlay on q/k/v/ctx (dead during MoE)
  float* YB  = ws + OF_PATCH;        // overlay on patches+ebuf (both dead by g2)
  u16* XNB   = (u16*)(ws + OF_PATCH);// overlay: dead before YB is written (g1 precedes g2)
  u16* W1T   = (u16*)(ws + OF_O1);   // overlay: o1 written only at combine (after g1)
  u16* W2T   = (u16*)(ws + OF_O2);   // overlay: o2 written only at layer-2 combine (after g2)

  float* out = (float*)d_out;
  float* out_logits = out;
  float* out_fv     = out + 16384;
  float* out_loss   = out + 32768;
  float* out_attnw  = out + 32769;

  k_patchify<<<18816, 256, 0, stream>>>(x, patches);
  k_gemm<0><<<dim3(4, 64), 256, 0, stream>>>(patches, pe_w, ebuf, 8192, 512, 588, pe_b, pos);
  k_ln<<<8192, 256, 0, stream>>>(ebuf, xn, XNB, ln1g, ln1b);
  k_gemm<1><<<dim3(4, 64), 256, 0, stream>>>(xn, wq, qb, 8192, 512, 512, bq, nullptr);
  k_gemm<1><<<dim3(4, 64), 256, 0, stream>>>(xn, wk, kb, 8192, 512, 512, bk, nullptr);
  k_gemm<1><<<dim3(4, 64), 256, 0, stream>>>(xn, wv, vb, 8192, 512, 512, bv, nullptr);
  k_attn<<<dim3(16, 32), 256, 0, stream>>>(qb, kb, vb, ctx, out_attnw);
  k_gemm<2><<<dim3(4, 64), 256, 0, stream>>>(ctx, wo, ebuf, 8192, 512, 512, bo, nullptr);  // e += ctx@wo + bo

  const float* moe_in[2] = {ebuf, o1};
  float* moe_out[2] = {o1, o2};
  for (int mi = 0; mi < 2; mi++) {
    hipMemsetAsync(imps, 0, 64, stream);   // zero imps(32B) + cnt(32B)
    k_ln<<<8192, 256, 0, stream>>>(moe_in[mi], xn, XNB, lng[mi], lnb[mi]);
    // weight cvt AFTER LN: layer-2 must consume o1 before W1T overlay clobbers it
    k_wcvt<<<dim3(16, 64, 8), 256, 0, stream>>>(m_w1[mi], W1T, 512, 2048);
    k_wcvt<<<dim3(64, 16, 8), 256, 0, stream>>>(m_w2[mi], W2T, 2048, 512);
    k_router<<<32, 256, 0, stream>>>(xn, m_rw[mi], m_rb[mi], gates, topi, cnt, imps);
    k_scan<<<1, 64, 0, stream>>>(cnt, basep, curs);
    k_scatter<<<32, 256, 0, stream>>>(topi, basep, curs, rowlist, rowpos);
    k_loss<<<1, 64, 0, stream>>>(cnt, imps, lossws, out_loss, mi);
    k_mg1<<<dim3(16, 64, 8), 256, 0, stream>>>(XNB, W1T, m_b1[mi], Hbuf, rowlist, basep, cnt);
    k_mg2<<<dim3(4, 64, 8), 256, 0, stream>>>(Hbuf, W2T, m_b2[mi], YB, basep, cnt);
    k_combine<<<16384, 256, 0, stream>>>(YB, gates, rowpos, moe_out[mi]);
  }
  k_fv<<<64, 256, 0, stream>>>(o2, fv, out_fv);
  k_cls<<<64, 256, 0, stream>>>(fv, cls_w, cls_b, out_logits);
}

// Round 4
// 1090.314 us; speedup vs baseline: 3.2349x; 1.6135x over previous
//
#include <hip/hip_runtime.h>
#include <hip/hip_bf16.h>

using bf16 = __hip_bfloat16;
typedef unsigned short u16;
typedef __attribute__((ext_vector_type(8))) short short8;
typedef __attribute__((ext_vector_type(4))) float f32x4;

#define DEVFN __device__ __forceinline__

DEVFN u16 f2bu(float v) { return __builtin_bit_cast(u16, __float2bfloat16(v)); }
DEVFN float us2f(u16 u) { union { unsigned int i; float f; } x; x.i = ((unsigned int)u) << 16; return x.f; }
DEVFN void unp8(uint4 u, float* f) {
  f[0]=us2f(u.x & 0xffffu); f[1]=us2f(u.x >> 16);
  f[2]=us2f(u.y & 0xffffu); f[3]=us2f(u.y >> 16);
  f[4]=us2f(u.z & 0xffffu); f[5]=us2f(u.z >> 16);
  f[6]=us2f(u.w & 0xffffu); f[7]=us2f(u.w >> 16);
}

DEVFN f32x4 mfma16(short8 a, short8 b, f32x4 c) {
  return __builtin_amdgcn_mfma_f32_16x16x32_bf16(a, b, c, 0, 0, 0);
}

// ---------------- workspace layout (float element offsets) ----------------
// total: 38,453,288 floats = ~147 MiB (unchanged from passing rounds)
static constexpr size_t OF_PATCH = 0;          // XP bf16 [8192,608] = 2,490,368 fl ; later XNB bf16 + YB f32
static constexpr size_t OF_E     = 4816896;    // ebuf f32 [8192,512]
static constexpr size_t OF_XN    = 9011200;    // xn f32 [8192,512]
static constexpr size_t OF_Q     = 13205504;
static constexpr size_t OF_FV    = 38371328;   // 32*512
static constexpr size_t OF_GATES = 38387712;   // 8192*2
static constexpr size_t OF_IMPS  = 38404096;   // 8 f32 (memset with CNT: 64B)
static constexpr size_t OF_CNT   = 38404104;   // 8 i32
static constexpr size_t OF_BASE  = 38404112;   // 8 i32
static constexpr size_t OF_CURS  = 38404120;   // 8 i32
static constexpr size_t OF_LOSS  = 38404128;   // 1 f32 (+pad)
static constexpr size_t OF_TOPI  = 38404136;   // 8192*2 i32
static constexpr size_t OF_RPOS  = 38420520;   // 8192*2 i32
static constexpr size_t OF_RLIST = 38436904;   // 16384 i32
// Pre-MoE sublayout of [OF_Q, OF_O1):
static constexpr size_t OF_Q16   = 13205504;   // bf16 [8192,512] = 2,097,152 fl
static constexpr size_t OF_K16   = 15302656;   // bf16 [8192,512]
static constexpr size_t OF_VT    = 17399808;   // bf16 [32,8,64,256] = 2,097,152 fl
static constexpr size_t OF_CTX16 = 19496960;   // bf16 [8192,512]
static constexpr size_t OF_WD    = 21594112;   // dense bf16 weights: peT 155648 + 4x131072 fl
static constexpr size_t OF_PET   = 21594112;
static constexpr size_t OF_WQT   = 21749760;
static constexpr size_t OF_WKT   = 21880832;
static constexpr size_t OF_WVT   = 22011904;
static constexpr size_t OF_WOT   = 22142976;   // ends 22274048 < OF_O1
static constexpr size_t OF_O1    = 29982720;   // o1 f32 ; earlier Pg bf16 [32,8,256,256] spans O1..FV ; W1T overlay
static constexpr size_t OF_O2    = 34177024;   // o2 f32 ; W2T overlay
// MoE overlays (lifetime-checked, as round 3):
//  H (bf16 16384x2048) on [OF_Q, OF_O1); YB f32 on [0, 8388608); XNB bf16 on [0, 2097152)

// ---------------- patchify: x[B,3,224,224] -> XP bf16 [8192,608] (zero-pad 588..607) ----------------
__global__ __launch_bounds__(256) void k_patchify(const float* __restrict__ x, u16* __restrict__ XP) {
  int idx = blockIdx.x * 256 + threadIdx.x;
  if (idx >= 8192 * 608) return;
  int row = idx / 608, j = idx - row * 608;
  u16 v = 0;
  if (j < 588) {
    int b = row >> 8, s = row & 255;
    int hh = s >> 4, ww = s & 15;
    int c = j % 3, tt = j / 3;
    int p2 = tt % 14, p1 = tt / 14;
    int src = ((b * 3 + c) * 224 + hh * 14 + p1) * 224 + (ww * 14 + p2);
    v = f2bu(x[src]);
  }
  XP[idx] = v;
}

// ---------------- dense weight cvt+transpose: W[K,512] f32 -> WT[512,KP] bf16 (zero-pad K..KP) ----------------
__global__ __launch_bounds__(256) void k_wcvtd(const float* __restrict__ W, u16* __restrict__ WT, int K, int KP)
{
  __shared__ float s[32][33];
  const int t = threadIdx.x;
  const int tx = t & 31, ty = t >> 5;
  const int k0 = blockIdx.x * 32, n0 = blockIdx.y * 32;
#pragma unroll
  for (int i = 0; i < 4; i++) {
    int kk = k0 + ty + i * 8;
    s[ty + i * 8][tx] = (kk < K) ? W[(size_t)kk * 512 + n0 + tx] : 0.f;
  }
  __syncthreads();
#pragma unroll
  for (int i = 0; i < 4; i++) WT[(size_t)(n0 + ty + i * 8) * KP + k0 + tx] = f2bu(s[tx][ty + i * 8]);
}

// ---------------- MoE weight cvt+transpose (per expert): W[K,N] f32 -> Wt[N,K] bf16 ----------------
__global__ __launch_bounds__(256) void k_wcvt(const float* __restrict__ W, u16* __restrict__ Wt, int K, int N)
{
  __shared__ float s[32][33];
  const int t = threadIdx.x;
  const int tx = t & 31, ty = t >> 5;
  const int k0 = blockIdx.x * 32, n0 = blockIdx.y * 32;
  const size_t es = (size_t)K * N;
  const float* We = W + (size_t)blockIdx.z * es;
  u16* Wte = Wt + (size_t)blockIdx.z * es;
#pragma unroll
  for (int i = 0; i < 4; i++) s[ty + i * 8][tx] = We[(size_t)(k0 + ty + i * 8) * N + n0 + tx];
  __syncthreads();
#pragma unroll
  for (int i = 0; i < 4; i++) Wte[(size_t)(n0 + ty + i * 8) * K + k0 + tx] = f2bu(s[tx][ty + i * 8]);
}

// ---------------- dense MFMA GEMM: C[8192,512] = A16[8192,K] @ BT16[512,K]^T ----------------
// MODE 0: f32 out + bias + pos (patch embed) ; MODE 1: bf16 out + bias (Q/K)
// MODE 2: f32 residual accumulate + bias (wo) ; MODE 3: bf16 V^T layout [b,h,d,s] + bias (V)
template<int MODE>
__global__ __launch_bounds__(256) void k_bgemm(const u16* __restrict__ A, const u16* __restrict__ BT,
    const float* __restrict__ bias, float* __restrict__ Cf, u16* __restrict__ O16,
    const float* __restrict__ pos, int K, int lda)
{
  const int m0 = blockIdx.y * 128, n0 = blockIdx.x * 128;
  __shared__ u16 As[128 * 40];
  __shared__ u16 Bs[128 * 40];
  const int t = threadIdx.x;
  const int r0 = t >> 2, c0 = (t & 3) * 8;
  const u16* pa0 = A + (size_t)(m0 + r0) * lda + c0;
  const u16* pa1 = A + (size_t)(m0 + r0 + 64) * lda + c0;
  const u16* pb0 = BT + (size_t)(n0 + r0) * K + c0;
  const u16* pb1 = BT + (size_t)(n0 + r0 + 64) * K + c0;
  u16* sa0 = &As[r0 * 40 + c0]; u16* sa1 = &As[(r0 + 64) * 40 + c0];
  u16* sb0 = &Bs[r0 * 40 + c0]; u16* sb1 = &Bs[(r0 + 64) * 40 + c0];
  const int lane = t & 63, wv = t >> 6;
  const int wm = (wv & 1) * 64, wn = (wv >> 1) * 64;
  const int ml = lane & 15, kq = lane >> 4;
  f32x4 acc[4][4];
#pragma unroll
  for (int i = 0; i < 4; i++)
#pragma unroll
    for (int j = 0; j < 4; j++) acc[i][j] = (f32x4){0.f, 0.f, 0.f, 0.f};
  for (int k0 = 0; k0 < K; k0 += 32) {
    uint4 ga0 = *(const uint4*)(pa0 + k0);
    uint4 ga1 = *(const uint4*)(pa1 + k0);
    uint4 gb0 = *(const uint4*)(pb0 + k0);
    uint4 gb1 = *(const uint4*)(pb1 + k0);
    __syncthreads();
    *(uint4*)sa0 = ga0; *(uint4*)sa1 = ga1;
    *(uint4*)sb0 = gb0; *(uint4*)sb1 = gb1;
    __syncthreads();
    short8 af[4], bf[4];
#pragma unroll
    for (int i = 0; i < 4; i++) af[i] = *(const short8*)&As[(wm + i * 16 + ml) * 40 + kq * 8];
#pragma unroll
    for (int j = 0; j < 4; j++) bf[j] = *(const short8*)&Bs[(wn + j * 16 + ml) * 40 + kq * 8];
#pragma unroll
    for (int i = 0; i < 4; i++)
#pragma unroll
      for (int j = 0; j < 4; j++) acc[i][j] = mfma16(af[i], bf[j], acc[i][j]);
  }
#pragma unroll
  for (int j = 0; j < 4; j++) {
    const int n = n0 + wn + j * 16 + ml;
    const float bv = bias[n];
#pragma unroll
    for (int i = 0; i < 4; i++) {
      const int mb = m0 + wm + i * 16 + kq * 4;
      if (MODE == 3) {
        const int b = mb >> 8, s0 = mb & 255;
        const int h = n >> 6, d = n & 63;
        ushort4 w4;
        w4.x = f2bu(acc[i][j][0] + bv); w4.y = f2bu(acc[i][j][1] + bv);
        w4.z = f2bu(acc[i][j][2] + bv); w4.w = f2bu(acc[i][j][3] + bv);
        *(ushort4*)(O16 + ((size_t)(b * 8 + h) * 64 + d) * 256 + s0) = w4;
      } else {
#pragma unroll
        for (int r = 0; r < 4; r++) {
          const int m = mb + r;
          const float v = acc[i][j][r] + bv;
          if (MODE == 0) Cf[(size_t)m * 512 + n] = v + pos[(size_t)(m & 255) * 512 + n];
          else if (MODE == 1) O16[(size_t)m * 512 + n] = f2bu(v);
          else if (MODE == 2) Cf[(size_t)m * 512 + n] += v;
        }
      }
    }
  }
}

// ---------------- LayerNorm over D=512 (writes f32 + bf16 copies) ----------------
__global__ __launch_bounds__(256) void k_ln(const float* __restrict__ X, float* __restrict__ Y,
    u16* __restrict__ YB16, const float* __restrict__ g, const float* __restrict__ b)
{
  __shared__ float red[256];
  const int row = blockIdx.x;
  const int t = threadIdx.x;
  const float* xr = X + (size_t)row * 512;
  float x0 = xr[t], x1 = xr[t + 256];
  red[t] = x0 + x1;
  __syncthreads();
  for (int s = 128; s > 0; s >>= 1) { if (t < s) red[t] += red[t + s]; __syncthreads(); }
  float mean = red[0] * (1.f / 512.f);
  __syncthreads();
  float d0 = x0 - mean, d1 = x1 - mean;
  red[t] = d0 * d0 + d1 * d1;
  __syncthreads();
  for (int s = 128; s > 0; s >>= 1) { if (t < s) red[t] += red[t + s]; __syncthreads(); }
  float rs = 1.f / sqrtf(red[0] * (1.f / 512.f) + 1e-5f);
  float y0 = d0 * rs * g[t]       + b[t];
  float y1 = d1 * rs * g[t + 256] + b[t + 256];
  float* yr = Y + (size_t)row * 512;
  yr[t] = y0; yr[t + 256] = y1;
  u16* br16 = YB16 + (size_t)row * 512;
  br16[t] = f2bu(y0); br16[t + 256] = f2bu(y1);
}

// ---------------- MFMA attention: per (qtile64, head, batch) ----------------
// Q A-frags from global; K staged in LDS; S in registers; softmax in registers;
// P -> LDS (A layout) + Pg global; V^T staged in LDS halves; O -> ctx16.
__global__ __launch_bounds__(256) void k_fattn(const u16* __restrict__ Q16, const u16* __restrict__ K16,
    const u16* __restrict__ VT, u16* __restrict__ CTX16, u16* __restrict__ Pg)
{
  __shared__ u16 P[64 * 264];
  __shared__ u16 kv[64 * 136];
  const int t = threadIdx.x;
  const int qt = blockIdx.x, h = blockIdx.y, b = blockIdx.z;
  const int q0 = qt * 64;
  const int lane = t & 63, w = t >> 6;
  const int ml = lane & 15, kq = lane >> 4;
  const int srow = t >> 2, spart = t & 3;

  // A-fragments for this wave's 16 q rows (row = ml), k = d
  const size_t tokq = (size_t)(b * 256 + q0 + w * 16 + ml);
  short8 aq0 = *(const short8*)(Q16 + tokq * 512 + h * 64 + kq * 8);
  short8 aq1 = *(const short8*)(Q16 + tokq * 512 + h * 64 + 32 + kq * 8);

  f32x4 sacc[16];
#pragma unroll
  for (int i = 0; i < 16; i++) sacc[i] = (f32x4){0.f, 0.f, 0.f, 0.f};

  // ---- phase 1: S = Q K^T ----
  for (int kc = 0; kc < 4; kc++) {
    __syncthreads();
    {
      const u16* src = K16 + (size_t)(b * 256 + kc * 64 + srow) * 512 + h * 64 + spart * 16;
      uint4 v0 = *(const uint4*)src;
      uint4 v1 = *(const uint4*)(src + 8);
      *(uint4*)&kv[srow * 72 + spart * 16] = v0;
      *(uint4*)&kv[srow * 72 + spart * 16 + 8] = v1;
    }
    __syncthreads();
#pragma unroll
    for (int kt = 0; kt < 4; kt++) {
      short8 bk0 = *(const short8*)&kv[(kt * 16 + ml) * 72 + kq * 8];
      short8 bk1 = *(const short8*)&kv[(kt * 16 + ml) * 72 + 32 + kq * 8];
      sacc[kc * 4 + kt] = mfma16(aq0, bk0, sacc[kc * 4 + kt]);
      sacc[kc * 4 + kt] = mfma16(aq1, bk1, sacc[kc * 4 + kt]);
    }
  }

  // ---- softmax (rows kq*4+r, cols tile*16+ml), scale 1/8 ----
#pragma unroll
  for (int r = 0; r < 4; r++) {
    float v[16];
    float mx = -1e30f;
#pragma unroll
    for (int tl = 0; tl < 16; tl++) { v[tl] = sacc[tl][r] * 0.125f; mx = fmaxf(mx, v[tl]); }
#pragma unroll
    for (int mk = 1; mk < 16; mk <<= 1) mx = fmaxf(mx, __shfl_xor(mx, mk, 64));
    float sum = 0.f;
#pragma unroll
    for (int tl = 0; tl < 16; tl++) { v[tl] = __expf(v[tl] - mx); sum += v[tl]; }
#pragma unroll
    for (int mk = 1; mk < 16; mk <<= 1) sum += __shfl_xor(sum, mk, 64);
    float inv = 1.f / sum;
    const int qrow = w * 16 + kq * 4 + r;
#pragma unroll
    for (int tl = 0; tl < 16; tl++) P[qrow * 264 + tl * 16 + ml] = f2bu(v[tl] * inv);
  }
  __syncthreads();   // make P visible (cross-lane copy + frag reads below)

  // ---- copy own wave's P rows to global Pg (coalesced b128) ----
  {
    const int row_l = w * 16 + (lane >> 2);
    const int cp0 = (lane & 3) * 64;
    u16* dst = Pg + ((size_t)(b * 8 + h) * 256 + q0 + row_l) * 256 + cp0;
    const u16* srcl = &P[row_l * 264 + cp0];
#pragma unroll
    for (int i = 0; i < 8; i++) *(uint4*)(dst + i * 8) = *(const uint4*)(srcl + i * 8);
  }

  // ---- phase 2: O = P V  (V^T staged in halves of 128 keys) ----
  f32x4 oacc[4];
#pragma unroll
  for (int j = 0; j < 4; j++) oacc[j] = (f32x4){0.f, 0.f, 0.f, 0.f};
  for (int half = 0; half < 2; half++) {
    __syncthreads();
    {
      const u16* src = VT + ((size_t)(b * 8 + h) * 64 + srow) * 256 + half * 128 + spart * 32;
#pragma unroll
      for (int i = 0; i < 4; i++)
        *(uint4*)&kv[srow * 136 + spart * 32 + i * 8] = *(const uint4*)(src + i * 8);
    }
    __syncthreads();
#pragma unroll
    for (int st = 0; st < 4; st++) {
      short8 ap = *(const short8*)&P[(w * 16 + ml) * 264 + half * 128 + st * 32 + kq * 8];
#pragma unroll
      for (int j = 0; j < 4; j++) {
        short8 bv = *(const short8*)&kv[(j * 16 + ml) * 136 + st * 32 + kq * 8];
        oacc[j] = mfma16(ap, bv, oacc[j]);
      }
    }
  }

  // ---- write ctx16[token][h*64 + d] ----
#pragma unroll
  for (int j = 0; j < 4; j++) {
    const int d = h * 64 + j * 16 + ml;
#pragma unroll
    for (int r = 0; r < 4; r++) {
      const int tok = b * 256 + q0 + w * 16 + kq * 4 + r;
      CTX16[(size_t)tok * 512 + d] = f2bu(oacc[j][r]);
    }
  }
}

// ---------------- attn_w = softmax(mean over heads of Pg) ----------------
__global__ __launch_bounds__(256) void k_attnw(const u16* __restrict__ Pg, float* __restrict__ AW)
{
  const int t = threadIdx.x;
  const int qt = blockIdx.x, b = blockIdx.y;
  const int row = t >> 4, seg = t & 15;
  const int q = qt * 16 + row;
  float vals[16];
#pragma unroll
  for (int i = 0; i < 16; i++) vals[i] = 0.f;
#pragma unroll
  for (int h = 0; h < 8; h++) {
    const u16* src = Pg + ((size_t)(b * 8 + h) * 256 + q) * 256 + seg * 16;
    uint4 u0 = *(const uint4*)src;
    uint4 u1 = *(const uint4*)(src + 8);
    float f0[8], f1[8];
    unp8(u0, f0); unp8(u1, f1);
#pragma unroll
    for (int i = 0; i < 8; i++) { vals[i] += f0[i]; vals[8 + i] += f1[i]; }
  }
  float vmax = -1e30f;
#pragma unroll
  for (int i = 0; i < 16; i++) { vals[i] *= 0.125f; vmax = fmaxf(vmax, vals[i]); }
#pragma unroll
  for (int mk = 1; mk < 16; mk <<= 1) vmax = fmaxf(vmax, __shfl_xor(vmax, mk, 64));
  float ssum = 0.f;
#pragma unroll
  for (int i = 0; i < 16; i++) { vals[i] = __expf(vals[i] - vmax); ssum += vals[i]; }
#pragma unroll
  for (int mk = 1; mk < 16; mk <<= 1) ssum += __shfl_xor(ssum, mk, 64);
  float inv = 1.f / ssum;
  float* orow = AW + (size_t)(b * 256 + q) * 256 + seg * 16;
#pragma unroll
  for (int i = 0; i < 16; i++) orow[i] = vals[i] * inv;
}

// ---------------- router (fp32, unchanged) ----------------
DEVFN int rwidx(int k, int e) { return k * 8 + e + (k >> 6) * 4; }

__global__ __launch_bounds__(256) void k_router(const float* __restrict__ XNp, const float* __restrict__ rw,
    const float* __restrict__ rb, float* __restrict__ gates, int* __restrict__ topi,
    int* __restrict__ cnt, float* __restrict__ imps)
{
  __shared__ float rws[4128];
  const int t = threadIdx.x;
  for (int i = t; i < 4096; i += 256) rws[rwidx(i >> 3, i & 7)] = rw[i];
  __syncthreads();
  const int w = t >> 6, l = t & 63;
  const int e = l & 7, ch = l >> 3;
  float impAcc = 0.f; int cntAcc = 0;
  const int row0 = blockIdx.x * 256 + w * 64;
  for (int r = 0; r < 64; r++) {
    const int row = row0 + r;
    const float* xr = XNp + (size_t)row * 512 + ch * 64;
    float s = 0.f;
#pragma unroll 8
    for (int j = 0; j < 64; j++) s = fmaf(xr[j], rws[rwidx(ch * 64 + j, e)], s);
    s += __shfl_xor(s, 8, 64);
    s += __shfl_xor(s, 16, 64);
    s += __shfl_xor(s, 32, 64);
    s += rb[e];
    float p[8];
#pragma unroll
    for (int i = 0; i < 8; i++) p[i] = __shfl(s, (l & 56) | i, 64);
    float mx = p[0];
#pragma unroll
    for (int i = 1; i < 8; i++) mx = fmaxf(mx, p[i]);
    float sum = 0.f;
#pragma unroll
    for (int i = 0; i < 8; i++) { p[i] = __expf(p[i] - mx); sum += p[i]; }
    float inv = 1.f / sum;
#pragma unroll
    for (int i = 0; i < 8; i++) p[i] *= inv;
    int t0 = 0; float v0 = p[0];
#pragma unroll
    for (int i = 1; i < 8; i++) if (p[i] > v0) { v0 = p[i]; t0 = i; }
    int t1 = -1; float v1 = -1.f;
#pragma unroll
    for (int i = 0; i < 8; i++) if (i != t0 && p[i] > v1) { v1 = p[i]; t1 = i; }
    if (l < 8) { impAcc += p[e]; cntAcc += (t0 == e) + (t1 == e); }
    if (l == 0) {
      gates[(size_t)row * 2] = v0; gates[(size_t)row * 2 + 1] = v1;
      topi[(size_t)row * 2] = t0;  topi[(size_t)row * 2 + 1] = t1;
    }
  }
  if (l < 8) { atomicAdd(&imps[e], impAcc); atomicAdd(&cnt[e], cntAcc); }
}

__global__ void k_scan(const int* __restrict__ cnt, int* __restrict__ basep, int* __restrict__ curs) {
  if (threadIdx.x == 0) {
    int a = 0;
    for (int e = 0; e < 8; e++) { basep[e] = a; a += cnt[e]; }
  }
  if (threadIdx.x < 8) curs[threadIdx.x] = 0;
}

__global__ __launch_bounds__(256) void k_scatter(const int* __restrict__ topi, const int* __restrict__ basep,
    int* __restrict__ cursor, int* __restrict__ rowlist, int* __restrict__ rowpos)
{
  __shared__ int lcnt[8], lbase[8];
  const int t = threadIdx.x;
  if (t < 8) lcnt[t] = 0;
  __syncthreads();
  const int token = blockIdx.x * 256 + t;
  const int e0 = topi[token * 2], e1 = topi[token * 2 + 1];
  const int p0 = atomicAdd(&lcnt[e0], 1);
  const int p1 = atomicAdd(&lcnt[e1], 1);
  __syncthreads();
  if (t < 8) lbase[t] = atomicAdd(&cursor[t], lcnt[t]);
  __syncthreads();
  const int pos0 = basep[e0] + lbase[e0] + p0;
  const int pos1 = basep[e1] + lbase[e1] + p1;
  rowlist[pos0] = token; rowlist[pos1] = token;
  rowpos[token * 2] = pos0; rowpos[token * 2 + 1] = pos1;
}

__global__ void k_loss(const int* __restrict__ cnt, const float* __restrict__ imps,
                       float* __restrict__ lossws, float* __restrict__ out, int phase) {
  if (threadIdx.x == 0 && blockIdx.x == 0) {
    float s = 0.f;
    for (int e = 0; e < 8; e++) s += ((float)cnt[e]) * imps[e];
    s *= 8.f / (8192.f * 8192.f);
    if (phase == 0) *lossws = s;
    else out[0] = *lossws + s;
  }
}

// ---------------- MFMA expert GEMM1 (unchanged from round 3) ----------------
__global__ __launch_bounds__(256) void k_mg1(const u16* __restrict__ XNB, const u16* __restrict__ W1T,
    const float* __restrict__ B1, u16* __restrict__ H,
    const int* __restrict__ rowlist, const int* __restrict__ basep, const int* __restrict__ cntp)
{
  const int e = blockIdx.z;
  const int cnt = cntp[e];
  const int m0 = blockIdx.y * 128;
  if (m0 >= cnt) return;
  const int base = basep[e];
  const int n0 = blockIdx.x * 128;
  __shared__ u16 As[128 * 40];
  __shared__ u16 Bs[128 * 40];
  __shared__ int rl[128];
  const int t = threadIdx.x;
  if (t < 128) rl[t] = rowlist[base + min(m0 + t, cnt - 1)];
  __syncthreads();
  const int r0 = t >> 2, c0 = (t & 3) * 8;
  const u16* pa0 = XNB + (size_t)rl[r0] * 512 + c0;
  const u16* pa1 = XNB + (size_t)rl[r0 + 64] * 512 + c0;
  const u16* wt = W1T + (size_t)e * (2048 * 512);
  const u16* pb0 = wt + (size_t)(n0 + r0) * 512 + c0;
  const u16* pb1 = wt + (size_t)(n0 + r0 + 64) * 512 + c0;
  u16* sa0 = &As[r0 * 40 + c0]; u16* sa1 = &As[(r0 + 64) * 40 + c0];
  u16* sb0 = &Bs[r0 * 40 + c0]; u16* sb1 = &Bs[(r0 + 64) * 40 + c0];
  const int lane = t & 63, wv = t >> 6;
  const int wm = (wv & 1) * 64, wn = (wv >> 1) * 64;
  const int ml = lane & 15, kq = lane >> 4;
  f32x4 acc[4][4];
#pragma unroll
  for (int i = 0; i < 4; i++)
#pragma unroll
    for (int j = 0; j < 4; j++) acc[i][j] = (f32x4){0.f, 0.f, 0.f, 0.f};
  for (int k0 = 0; k0 < 512; k0 += 32) {
    uint4 ga0 = *(const uint4*)(pa0 + k0);
    uint4 ga1 = *(const uint4*)(pa1 + k0);
    uint4 gb0 = *(const uint4*)(pb0 + k0);
    uint4 gb1 = *(const uint4*)(pb1 + k0);
    __syncthreads();
    *(uint4*)sa0 = ga0; *(uint4*)sa1 = ga1;
    *(uint4*)sb0 = gb0; *(uint4*)sb1 = gb1;
    __syncthreads();
    short8 af[4], bf[4];
#pragma unroll
    for (int i = 0; i < 4; i++) af[i] = *(const short8*)&As[(wm + i * 16 + ml) * 40 + kq * 8];
#pragma unroll
    for (int j = 0; j < 4; j++) bf[j] = *(const short8*)&Bs[(wn + j * 16 + ml) * 40 + kq * 8];
#pragma unroll
    for (int i = 0; i < 4; i++)
#pragma unroll
      for (int j = 0; j < 4; j++) acc[i][j] = mfma16(af[i], bf[j], acc[i][j]);
  }
#pragma unroll
  for (int j = 0; j < 4; j++) {
    const int n = n0 + wn + j * 16 + ml;
    const float bv = B1[e * 2048 + n];
#pragma unroll
    for (int i = 0; i < 4; i++) {
#pragma unroll
      for (int r = 0; r < 4; r++) {
        const int lr = wm + i * 16 + kq * 4 + r;
        if (m0 + lr < cnt) {
          float v = acc[i][j][r] + bv;
          float g = 0.5f * v * (1.f + erff(v * 0.70710678118654752f));
          H[(size_t)(base + m0 + lr) * 2048 + n] = f2bu(g);
        }
      }
    }
  }
}

// ---------------- MFMA expert GEMM2 (unchanged from round 3) ----------------
__global__ __launch_bounds__(256) void k_mg2(const u16* __restrict__ H, const u16* __restrict__ W2T,
    const float* __restrict__ B2, float* __restrict__ YB,
    const int* __restrict__ basep, const int* __restrict__ cntp)
{
  const int e = blockIdx.z;
  const int cnt = cntp[e];
  const int m0 = blockIdx.y * 128;
  if (m0 >= cnt) return;
  const int base = basep[e];
  const int n0 = blockIdx.x * 128;
  __shared__ u16 As[128 * 40];
  __shared__ u16 Bs[128 * 40];
  const int t = threadIdx.x;
  const int r0 = t >> 2, c0 = (t & 3) * 8;
  const int gr0 = min(base + m0 + r0, 16383);
  const int gr1 = min(base + m0 + r0 + 64, 16383);
  const u16* pa0 = H + (size_t)gr0 * 2048 + c0;
  const u16* pa1 = H + (size_t)gr1 * 2048 + c0;
  const u16* wt = W2T + (size_t)e * (512 * 2048);
  const u16* pb0 = wt + (size_t)(n0 + r0) * 2048 + c0;
  const u16* pb1 = wt + (size_t)(n0 + r0 + 64) * 2048 + c0;
  u16* sa0 = &As[r0 * 40 + c0]; u16* sa1 = &As[(r0 + 64) * 40 + c0];
  u16* sb0 = &Bs[r0 * 40 + c0]; u16* sb1 = &Bs[(r0 + 64) * 40 + c0];
  const int lane = t & 63, wv = t >> 6;
  const int wm = (wv & 1) * 64, wn = (wv >> 1) * 64;
  const int ml = lane & 15, kq = lane >> 4;
  f32x4 acc[4][4];
#pragma unroll
  for (int i = 0; i < 4; i++)
#pragma unroll
    for (int j = 0; j < 4; j++) acc[i][j] = (f32x4){0.f, 0.f, 0.f, 0.f};
  for (int k0 = 0; k0 < 2048; k0 += 32) {
    uint4 ga0 = *(const uint4*)(pa0 + k0);
    uint4 ga1 = *(const uint4*)(pa1 + k0);
    uint4 gb0 = *(const uint4*)(pb0 + k0);
    uint4 gb1 = *(const uint4*)(pb1 + k0);
    __syncthreads();
    *(uint4*)sa0 = ga0; *(uint4*)sa1 = ga1;
    *(uint4*)sb0 = gb0; *(uint4*)sb1 = gb1;
    __syncthreads();
    short8 af[4], bf[4];
#pragma unroll
    for (int i = 0; i < 4; i++) af[i] = *(const short8*)&As[(wm + i * 16 + ml) * 40 + kq * 8];
#pragma unroll
    for (int j = 0; j < 4; j++) bf[j] = *(const short8*)&Bs[(wn + j * 16 + ml) * 40 + kq * 8];
#pragma unroll
    for (int i = 0; i < 4; i++)
#pragma unroll
      for (int j = 0; j < 4; j++) acc[i][j] = mfma16(af[i], bf[j], acc[i][j]);
  }
#pragma unroll
  for (int j = 0; j < 4; j++) {
    const int n = n0 + wn + j * 16 + ml;
    const float bv = B2[e * 512 + n];
#pragma unroll
    for (int i = 0; i < 4; i++) {
#pragma unroll
      for (int r = 0; r < 4; r++) {
        const int lr = wm + i * 16 + kq * 4 + r;
        if (m0 + lr < cnt)
          YB[(size_t)(base + m0 + lr) * 512 + n] = acc[i][j][r] + bv;
      }
    }
  }
}

// ---------------- combine / fv / cls ----------------
__global__ __launch_bounds__(256) void k_combine(const float* __restrict__ YB, const float* __restrict__ gates,
    const int* __restrict__ rowpos, float* __restrict__ OUT)
{
  const int idx = blockIdx.x * 256 + threadIdx.x;
  const int row = idx >> 9, d = idx & 511;
  const float g0 = gates[row * 2], g1 = gates[row * 2 + 1];
  const int r0 = rowpos[row * 2], r1 = rowpos[row * 2 + 1];
  OUT[idx] = g0 * YB[(size_t)r0 * 512 + d] + g1 * YB[(size_t)r1 * 512 + d];
}

__global__ __launch_bounds__(256) void k_fv(const float* __restrict__ O2, float* __restrict__ FVp, float* __restrict__ outv) {
  const int idx = blockIdx.x * 256 + threadIdx.x;  // 16384
  const int b = idx >> 9, d = idx & 511;
  const float* p = O2 + (size_t)b * 131072 + d;
  float s = 0.f;
  for (int i = 0; i < 256; i++) s += p[i * 512];
  s *= (1.f / 256.f);
  FVp[idx] = s;
  outv[idx] = s;
}

__global__ __launch_bounds__(256) void k_cls(const float* __restrict__ FVp, const float* __restrict__ W,
    const float* __restrict__ bias, float* __restrict__ outl) {
  const int idx = blockIdx.x * 256 + threadIdx.x;  // 16384
  const int b = idx >> 9, n = idx & 511;
  const float* f = FVp + (size_t)b * 512;
  float s = 0.f;
  for (int d = 0; d < 512; d++) s = fmaf(f[d], W[(size_t)d * 512 + n], s);
  s += bias[n];
  outl[idx] = s;
}

extern "C" void kernel_launch(void* const* d_in, const int* in_sizes, int n_in,
                              void* d_out, int out_size, void* d_ws, size_t ws_size,
                              hipStream_t stream)
{
  (void)in_sizes; (void)n_in; (void)out_size; (void)ws_size;
  const float* x    = (const float*)d_in[0];
  const float* pe_w = (const float*)d_in[1];
  const float* pe_b = (const float*)d_in[2];
  const float* pos  = (const float*)d_in[3];
  const float* ln1g = (const float*)d_in[4];
  const float* ln1b = (const float*)d_in[5];
  const float* lng[2] = {(const float*)d_in[6], (const float*)d_in[8]};
  const float* lnb[2] = {(const float*)d_in[7], (const float*)d_in[9]};
  const float* wq = (const float*)d_in[10]; const float* bq = (const float*)d_in[11];
  const float* wk = (const float*)d_in[12]; const float* bk = (const float*)d_in[13];
  const float* wv = (const float*)d_in[14]; const float* bv = (const float*)d_in[15];
  const float* wo = (const float*)d_in[16]; const float* bo = (const float*)d_in[17];
  const float* m_rw[2] = {(const float*)d_in[18], (const float*)d_in[24]};
  const float* m_rb[2] = {(const float*)d_in[19], (const float*)d_in[25]};
  const float* m_w1[2] = {(const float*)d_in[20], (const float*)d_in[26]};
  const float* m_b1[2] = {(const float*)d_in[21], (const float*)d_in[27]};
  const float* m_w2[2] = {(const float*)d_in[22], (const float*)d_in[28]};
  const float* m_b2[2] = {(const float*)d_in[23], (const float*)d_in[29]};
  const float* cls_w = (const float*)d_in[30];
  const float* cls_b = (const float*)d_in[31];

  float* ws = (float*)d_ws;
  u16* XP    = (u16*)(ws + OF_PATCH);
  float* ebuf = ws + OF_E;
  float* xn   = ws + OF_XN;
  u16* Q16   = (u16*)(ws + OF_Q16);
  u16* K16   = (u16*)(ws + OF_K16);
  u16* VTb   = (u16*)(ws + OF_VT);
  u16* ctx16 = (u16*)(ws + OF_CTX16);
  u16* peT   = (u16*)(ws + OF_PET);
  u16* wqT   = (u16*)(ws + OF_WQT);
  u16* wkT   = (u16*)(ws + OF_WKT);
  u16* wvT   = (u16*)(ws + OF_WVT);
  u16* woT   = (u16*)(ws + OF_WOT);
  u16* Pgb   = (u16*)(ws + OF_O1);   // 32MB, dead after k_attnw
  float* o1   = ws + OF_O1;
  float* o2   = ws + OF_O2;
  float* fv   = ws + OF_FV;
  float* gates = ws + OF_GATES;
  float* imps  = ws + OF_IMPS;
  int* cnt    = (int*)(ws + OF_CNT);
  int* basep  = (int*)(ws + OF_BASE);
  int* curs   = (int*)(ws + OF_CURS);
  float* lossws = ws + OF_LOSS;
  int* topi   = (int*)(ws + OF_TOPI);
  int* rowpos = (int*)(ws + OF_RPOS);
  int* rowlist= (int*)(ws + OF_RLIST);
  u16* Hbuf  = (u16*)(ws + OF_Q);    // MoE overlay on [OF_Q, OF_O1)
  float* YB  = ws + OF_PATCH;        // MoE overlay
  u16* XNB   = (u16*)(ws + OF_PATCH);// bf16 xn (written by k_ln; XP dead post-pe-GEMM)
  u16* W1T   = (u16*)(ws + OF_O1);   // MoE overlay (after Pg dead)
  u16* W2T   = (u16*)(ws + OF_O2);

  float* out = (float*)d_out;
  float* out_logits = out;
  float* out_fv     = out + 16384;
  float* out_loss   = out + 32768;
  float* out_attnw  = out + 32769;

  // ---- dense weight prep ----
  k_wcvtd<<<dim3(19, 16), 256, 0, stream>>>(pe_w, peT, 588, 608);
  k_wcvtd<<<dim3(16, 16), 256, 0, stream>>>(wq, wqT, 512, 512);
  k_wcvtd<<<dim3(16, 16), 256, 0, stream>>>(wk, wkT, 512, 512);
  k_wcvtd<<<dim3(16, 16), 256, 0, stream>>>(wv, wvT, 512, 512);
  k_wcvtd<<<dim3(16, 16), 256, 0, stream>>>(wo, woT, 512, 512);

  k_patchify<<<19456, 256, 0, stream>>>(x, XP);
  k_bgemm<0><<<dim3(4, 64), 256, 0, stream>>>(XP, peT, pe_b, ebuf, nullptr, pos, 608, 608);
  k_ln<<<8192, 256, 0, stream>>>(ebuf, xn, XNB, ln1g, ln1b);
  k_bgemm<1><<<dim3(4, 64), 256, 0, stream>>>(XNB, wqT, bq, nullptr, Q16, nullptr, 512, 512);
  k_bgemm<1><<<dim3(4, 64), 256, 0, stream>>>(XNB, wkT, bk, nullptr, K16, nullptr, 512, 512);
  k_bgemm<3><<<dim3(4, 64), 256, 0, stream>>>(XNB, wvT, bv, nullptr, VTb, nullptr, 512, 512);
  k_fattn<<<dim3(4, 8, 32), 256, 0, stream>>>(Q16, K16, VTb, ctx16, Pgb);
  k_attnw<<<dim3(16, 32), 256, 0, stream>>>(Pgb, out_attnw);
  k_bgemm<2><<<dim3(4, 64), 256, 0, stream>>>(ctx16, woT, bo, ebuf, nullptr, nullptr, 512, 512);

  const float* moe_in[2] = {ebuf, o1};
  float* moe_out[2] = {o1, o2};
  for (int mi = 0; mi < 2; mi++) {
    hipMemsetAsync(imps, 0, 64, stream);   // zero imps(32B) + cnt(32B)
    k_ln<<<8192, 256, 0, stream>>>(moe_in[mi], xn, XNB, lng[mi], lnb[mi]);
    // weight cvt AFTER LN: layer-2 must consume o1 before W1T overlay clobbers it
    k_wcvt<<<dim3(16, 64, 8), 256, 0, stream>>>(m_w1[mi], W1T, 512, 2048);
    k_wcvt<<<dim3(64, 16, 8), 256, 0, stream>>>(m_w2[mi], W2T, 2048, 512);
    k_router<<<32, 256, 0, stream>>>(xn, m_rw[mi], m_rb[mi], gates, topi, cnt, imps);
    k_scan<<<1, 64, 0, stream>>>(cnt, basep, curs);
    k_scatter<<<32, 256, 0, stream>>>(topi, basep, curs, rowlist, rowpos);
    k_loss<<<1, 64, 0, stream>>>(cnt, imps, lossws, out_loss, mi);
    k_mg1<<<dim3(16, 64, 8), 256, 0, stream>>>(XNB, W1T, m_b1[mi], Hbuf, rowlist, basep, cnt);
    k_mg2<<<dim3(4, 64, 8), 256, 0, stream>>>(Hbuf, W2T, m_b2[mi], YB, basep, cnt);
    k_combine<<<16384, 256, 0, stream>>>(YB, gates, rowpos, moe_out[mi]);
  }
  k_fv<<<64, 256, 0, stream>>>(o2, fv, out_fv);
  k_cls<<<64, 256, 0, stream>>>(fv, cls_w, cls_b, out_logits);
}

// Round 5
// 1057.266 us; speedup vs baseline: 3.3361x; 1.0313x over previous
//
#include <hip/hip_runtime.h>
#include <hip/hip_bf16.h>

using bf16 = __hip_bfloat16;
typedef unsigned short u16;
typedef __attribute__((ext_vector_type(8))) short short8;
typedef __attribute__((ext_vector_type(4))) float f32x4;

#define DEVFN __device__ __forceinline__

DEVFN u16 f2bu(float v) { return __builtin_bit_cast(u16, __float2bfloat16(v)); }
DEVFN float us2f(u16 u) { union { unsigned int i; float f; } x; x.i = ((unsigned int)u) << 16; return x.f; }
DEVFN void unp8(uint4 u, float* f) {
  f[0]=us2f(u.x & 0xffffu); f[1]=us2f(u.x >> 16);
  f[2]=us2f(u.y & 0xffffu); f[3]=us2f(u.y >> 16);
  f[4]=us2f(u.z & 0xffffu); f[5]=us2f(u.z >> 16);
  f[6]=us2f(u.w & 0xffffu); f[7]=us2f(u.w >> 16);
}

DEVFN f32x4 mfma16(short8 a, short8 b, f32x4 c) {
  return __builtin_amdgcn_mfma_f32_16x16x32_bf16(a, b, c, 0, 0, 0);
}

// async global->LDS, 16B per lane; LDS dest = wave-uniform base + lane*16
DEVFN void gl16(const u16* g, u16* l) {
  __builtin_amdgcn_global_load_lds((const __attribute__((address_space(1))) void*)g,
                                   (__attribute__((address_space(3))) void*)l, 16, 0, 0);
}

// ---------------- workspace layout (float element offsets) ----------------
static constexpr size_t OF_PATCH = 0;          // XP bf16 [8192,640] = 2,621,440 fl ; later XNB bf16 + YB f32
static constexpr size_t OF_E     = 4816896;    // ebuf f32 [8192,512]
static constexpr size_t OF_XN    = 9011200;    // xn f32 [8192,512]
static constexpr size_t OF_Q     = 13205504;
static constexpr size_t OF_FV    = 38371328;   // 32*512
static constexpr size_t OF_GATES = 38387712;   // 8192*2
static constexpr size_t OF_IMPS  = 38404096;   // 8 f32 (memset with CNT: 64B)
static constexpr size_t OF_CNT   = 38404104;   // 8 i32
static constexpr size_t OF_BASE  = 38404112;   // 8 i32
static constexpr size_t OF_CURS  = 38404120;   // 8 i32
static constexpr size_t OF_LOSS  = 38404128;   // 1 f32 (+pad)
static constexpr size_t OF_TOPI  = 38404136;   // 8192*2 i32
static constexpr size_t OF_RPOS  = 38420520;   // 8192*2 i32
static constexpr size_t OF_RLIST = 38436904;   // 16384 i32
// Pre-MoE sublayout of [OF_Q, OF_O1):
static constexpr size_t OF_Q16   = 13205504;   // bf16 [8192,512]
static constexpr size_t OF_K16   = 15302656;
static constexpr size_t OF_VT    = 17399808;   // bf16 [32,8,64,256]
static constexpr size_t OF_CTX16 = 19496960;   // bf16 [8192,512]
static constexpr size_t OF_PET   = 21594112;   // bf16 [512,640] = 163840 fl
static constexpr size_t OF_WQT   = 21757952;   // bf16 [512,512] = 131072 fl each
static constexpr size_t OF_WKT   = 21889024;
static constexpr size_t OF_WVT   = 22020096;
static constexpr size_t OF_WOT   = 22151168;   // ends 22282240 < OF_O1
static constexpr size_t OF_O1    = 29982720;   // o1 f32 ; earlier Pg bf16 spans O1..FV ; W1T overlay
static constexpr size_t OF_O2    = 34177024;   // o2 f32 ; W2T overlay
// MoE overlays: H (bf16 16384x2048) on [OF_Q, OF_O1); YB f32 on [0, 8388608); XNB bf16 on [0, 2097152)

// ---------------- patchify: x[B,3,224,224] -> XP bf16 [8192,640] (zero-pad 588..639) ----------------
__global__ __launch_bounds__(256) void k_patchify(const float* __restrict__ x, u16* __restrict__ XP) {
  int idx = blockIdx.x * 256 + threadIdx.x;
  if (idx >= 8192 * 640) return;
  int row = idx / 640, j = idx - row * 640;
  u16 v = 0;
  if (j < 588) {
    int b = row >> 8, s = row & 255;
    int hh = s >> 4, ww = s & 15;
    int c = j % 3, tt = j / 3;
    int p2 = tt % 14, p1 = tt / 14;
    int src = ((b * 3 + c) * 224 + hh * 14 + p1) * 224 + (ww * 14 + p2);
    v = f2bu(x[src]);
  }
  XP[idx] = v;
}

// ---------------- dense weight cvt+transpose: W[K,512] f32 -> WT[512,KP] bf16 ----------------
__global__ __launch_bounds__(256) void k_wcvtd(const float* __restrict__ W, u16* __restrict__ WT, int K, int KP)
{
  __shared__ float s[32][33];
  const int t = threadIdx.x;
  const int tx = t & 31, ty = t >> 5;
  const int k0 = blockIdx.x * 32, n0 = blockIdx.y * 32;
#pragma unroll
  for (int i = 0; i < 4; i++) {
    int kk = k0 + ty + i * 8;
    s[ty + i * 8][tx] = (kk < K) ? W[(size_t)kk * 512 + n0 + tx] : 0.f;
  }
  __syncthreads();
#pragma unroll
  for (int i = 0; i < 4; i++) WT[(size_t)(n0 + ty + i * 8) * KP + k0 + tx] = f2bu(s[tx][ty + i * 8]);
}

// ---------------- MoE weight cvt+transpose (per expert): W[K,N] f32 -> Wt[N,K] bf16 ----------------
__global__ __launch_bounds__(256) void k_wcvt(const float* __restrict__ W, u16* __restrict__ Wt, int K, int N)
{
  __shared__ float s[32][33];
  const int t = threadIdx.x;
  const int tx = t & 31, ty = t >> 5;
  const int k0 = blockIdx.x * 32, n0 = blockIdx.y * 32;
  const size_t es = (size_t)K * N;
  const float* We = W + (size_t)blockIdx.z * es;
  u16* Wte = Wt + (size_t)blockIdx.z * es;
#pragma unroll
  for (int i = 0; i < 4; i++) s[ty + i * 8][tx] = We[(size_t)(k0 + ty + i * 8) * N + n0 + tx];
  __syncthreads();
#pragma unroll
  for (int i = 0; i < 4; i++) Wte[(size_t)(n0 + ty + i * 8) * K + k0 + tx] = f2bu(s[tx][ty + i * 8]);
}

// ======== shared MFMA engine pieces ========
// LDS tile: [128 rows][64 u16], chunk c of row r stored at pos c^(r&7) (16B chunks).
// K-loop: BK=64, staged via global_load_lds (4 issues/tile), 2 mfma k-steps per iter.
DEVFN void mma_loop(f32x4 acc[4][4], const u16* const agp[4], const u16* const bgp[4],
                    u16* const alp[4], u16* const blp[4], u16* As, u16* Bs,
                    int K, int wm, int wn, int ml, int kq)
{
  for (int k0 = 0; k0 < K; k0 += 64) {
    __syncthreads();
#pragma unroll
    for (int q = 0; q < 4; q++) { gl16(agp[q] + k0, alp[q]); gl16(bgp[q] + k0, blp[q]); }
    __syncthreads();
#pragma unroll
    for (int ks = 0; ks < 2; ks++) {
      const int c = ks * 4 + kq;
      short8 af[4], bf[4];
#pragma unroll
      for (int i = 0; i < 4; i++) {
        const int row = wm + i * 16 + ml;
        af[i] = *(const short8*)&As[row * 64 + ((c ^ (row & 7)) << 3)];
      }
#pragma unroll
      for (int j = 0; j < 4; j++) {
        const int row = wn + j * 16 + ml;
        bf[j] = *(const short8*)&Bs[row * 64 + ((c ^ (row & 7)) << 3)];
      }
#pragma unroll
      for (int i = 0; i < 4; i++)
#pragma unroll
        for (int j = 0; j < 4; j++) acc[i][j] = mfma16(af[i], bf[j], acc[i][j]);
    }
  }
}

// per-wave 16x64 C sub-tile transpose through LDS; all threads must call (contains barriers)
DEVFN void ep_xpose(float* ep, const f32x4* ai, int kq, int ml, int er, int ec, float* v)
{
#pragma unroll
  for (int j = 0; j < 4; j++)
#pragma unroll
    for (int r = 0; r < 4; r++)
      ep[(kq * 4 + r) * 68 + j * 16 + ml] = ai[j][r];
  __syncthreads();
#pragma unroll
  for (int u = 0; u < 4; u++) {
    float4 f = *(const float4*)&ep[er * 68 + ec + u * 4];
    v[u * 4 + 0] = f.x; v[u * 4 + 1] = f.y; v[u * 4 + 2] = f.z; v[u * 4 + 3] = f.w;
  }
  __syncthreads();
}

// ---------------- dense MFMA GEMM: C[8192,512] = A16[8192,K] @ BT16[512,K]^T ----------------
// MODE 0: f32 + bias + pos ; MODE 1: bf16 + bias ; MODE 2: f32 residual += ; MODE 3: V^T bf16 [b,h,d,s]
template<int MODE>
__global__ __launch_bounds__(256) void k_bgemm(const u16* __restrict__ A, const u16* __restrict__ BT,
    const float* __restrict__ bias, float* __restrict__ Cf, u16* __restrict__ O16,
    const float* __restrict__ pos, int K)
{
  const int m0 = blockIdx.y * 128, n0 = blockIdx.x * 128;
  __shared__ u16 SB[16384];
  u16* As = SB; u16* Bs = SB + 8192;
  const int t = threadIdx.x;
  const int widx = t >> 6, lane = t & 63;
  const int wm = (widx & 1) * 64, wn = (widx >> 1) * 64;
  const int ml = lane & 15, kq = lane >> 4;
  const u16* agp[4]; const u16* bgp[4]; u16* alp[4]; u16* blp[4];
#pragma unroll
  for (int q = 0; q < 4; q++) {
    const int slot = q * 256 + t;
    const int row = slot >> 3;
    const int c = (slot & 7) ^ (row & 7);
    agp[q] = A + (size_t)(m0 + row) * K + c * 8;
    bgp[q] = BT + (size_t)(n0 + row) * K + c * 8;
    alp[q] = &As[(q * 256 + widx * 64) * 8];
    blp[q] = &Bs[(q * 256 + widx * 64) * 8];
  }
  f32x4 acc[4][4];
#pragma unroll
  for (int i = 0; i < 4; i++)
#pragma unroll
    for (int j = 0; j < 4; j++) acc[i][j] = (f32x4){0.f, 0.f, 0.f, 0.f};
  mma_loop(acc, agp, bgp, alp, blp, As, Bs, K, wm, wn, ml, kq);

  if (MODE == 3) {
    // direct epilogue: V^T [b,h,d,s], rows of acc are s (contiguous in r)
#pragma unroll
    for (int j = 0; j < 4; j++) {
      const int n = n0 + wn + j * 16 + ml;
      const float bv = bias[n];
      const int h = n >> 6, d = n & 63;
#pragma unroll
      for (int i = 0; i < 4; i++) {
        const int mb = m0 + wm + i * 16 + kq * 4;
        const int b = mb >> 8, s0 = mb & 255;
        ushort4 w4;
        w4.x = f2bu(acc[i][j][0] + bv); w4.y = f2bu(acc[i][j][1] + bv);
        w4.z = f2bu(acc[i][j][2] + bv); w4.w = f2bu(acc[i][j][3] + bv);
        *(ushort4*)(O16 + ((size_t)(b * 8 + h) * 64 + d) * 256 + s0) = w4;
      }
    }
    return;
  }

  __syncthreads();
  float* ep = (float*)SB + widx * (16 * 68);
  const int er = lane >> 2, ec = (lane & 3) * 16;
  const int gn = n0 + wn + ec;
  float bb[16];
#pragma unroll
  for (int u = 0; u < 4; u++) {
    float4 f = *(const float4*)(bias + gn + u * 4);
    bb[u*4]=f.x; bb[u*4+1]=f.y; bb[u*4+2]=f.z; bb[u*4+3]=f.w;
  }
#pragma unroll
  for (int i = 0; i < 4; i++) {
    float v[16];
    ep_xpose(ep, acc[i], kq, ml, er, ec, v);
    const int gm = m0 + wm + i * 16 + er;
    if (MODE == 0) {
      const float* pr = pos + (size_t)(gm & 255) * 512 + gn;
      float* cp = Cf + (size_t)gm * 512 + gn;
#pragma unroll
      for (int u = 0; u < 4; u++) {
        float4 p = *(const float4*)(pr + u * 4);
        float4 o = {v[u*4]+bb[u*4]+p.x, v[u*4+1]+bb[u*4+1]+p.y, v[u*4+2]+bb[u*4+2]+p.z, v[u*4+3]+bb[u*4+3]+p.w};
        *(float4*)(cp + u * 4) = o;
      }
    } else if (MODE == 1) {
      union { u16 h[16]; uint4 q2[2]; } pk;
#pragma unroll
      for (int u = 0; u < 16; u++) pk.h[u] = f2bu(v[u] + bb[u]);
      u16* hp = O16 + (size_t)gm * 512 + gn;
      *(uint4*)hp = pk.q2[0]; *(uint4*)(hp + 8) = pk.q2[1];
    } else {  // MODE 2
      float* cp = Cf + (size_t)gm * 512 + gn;
#pragma unroll
      for (int u = 0; u < 4; u++) {
        float4 oldv = *(const float4*)(cp + u * 4);
        float4 o = {oldv.x+v[u*4]+bb[u*4], oldv.y+v[u*4+1]+bb[u*4+1], oldv.z+v[u*4+2]+bb[u*4+2], oldv.w+v[u*4+3]+bb[u*4+3]};
        *(float4*)(cp + u * 4) = o;
      }
    }
  }
}

// ---------------- LayerNorm over D=512 (writes f32 + bf16 copies) ----------------
__global__ __launch_bounds__(256) void k_ln(const float* __restrict__ X, float* __restrict__ Y,
    u16* __restrict__ YB16, const float* __restrict__ g, const float* __restrict__ b)
{
  __shared__ float red[256];
  const int row = blockIdx.x;
  const int t = threadIdx.x;
  const float* xr = X + (size_t)row * 512;
  float x0 = xr[t], x1 = xr[t + 256];
  red[t] = x0 + x1;
  __syncthreads();
  for (int s = 128; s > 0; s >>= 1) { if (t < s) red[t] += red[t + s]; __syncthreads(); }
  float mean = red[0] * (1.f / 512.f);
  __syncthreads();
  float d0 = x0 - mean, d1 = x1 - mean;
  red[t] = d0 * d0 + d1 * d1;
  __syncthreads();
  for (int s = 128; s > 0; s >>= 1) { if (t < s) red[t] += red[t + s]; __syncthreads(); }
  float rs = 1.f / sqrtf(red[0] * (1.f / 512.f) + 1e-5f);
  float y0 = d0 * rs * g[t]       + b[t];
  float y1 = d1 * rs * g[t + 256] + b[t + 256];
  float* yr = Y + (size_t)row * 512;
  yr[t] = y0; yr[t + 256] = y1;
  u16* br16 = YB16 + (size_t)row * 512;
  br16[t] = f2bu(y0); br16[t + 256] = f2bu(y1);
}

// ---------------- MFMA attention (unchanged from round 4) ----------------
__global__ __launch_bounds__(256) void k_fattn(const u16* __restrict__ Q16, const u16* __restrict__ K16,
    const u16* __restrict__ VT, u16* __restrict__ CTX16, u16* __restrict__ Pg)
{
  __shared__ u16 P[64 * 264];
  __shared__ u16 kv[64 * 136];
  const int t = threadIdx.x;
  const int qt = blockIdx.x, h = blockIdx.y, b = blockIdx.z;
  const int q0 = qt * 64;
  const int lane = t & 63, w = t >> 6;
  const int ml = lane & 15, kq = lane >> 4;
  const int srow = t >> 2, spart = t & 3;

  const size_t tokq = (size_t)(b * 256 + q0 + w * 16 + ml);
  short8 aq0 = *(const short8*)(Q16 + tokq * 512 + h * 64 + kq * 8);
  short8 aq1 = *(const short8*)(Q16 + tokq * 512 + h * 64 + 32 + kq * 8);

  f32x4 sacc[16];
#pragma unroll
  for (int i = 0; i < 16; i++) sacc[i] = (f32x4){0.f, 0.f, 0.f, 0.f};

  for (int kc = 0; kc < 4; kc++) {
    __syncthreads();
    {
      const u16* src = K16 + (size_t)(b * 256 + kc * 64 + srow) * 512 + h * 64 + spart * 16;
      uint4 v0 = *(const uint4*)src;
      uint4 v1 = *(const uint4*)(src + 8);
      *(uint4*)&kv[srow * 72 + spart * 16] = v0;
      *(uint4*)&kv[srow * 72 + spart * 16 + 8] = v1;
    }
    __syncthreads();
#pragma unroll
    for (int kt = 0; kt < 4; kt++) {
      short8 bk0 = *(const short8*)&kv[(kt * 16 + ml) * 72 + kq * 8];
      short8 bk1 = *(const short8*)&kv[(kt * 16 + ml) * 72 + 32 + kq * 8];
      sacc[kc * 4 + kt] = mfma16(aq0, bk0, sacc[kc * 4 + kt]);
      sacc[kc * 4 + kt] = mfma16(aq1, bk1, sacc[kc * 4 + kt]);
    }
  }

#pragma unroll
  for (int r = 0; r < 4; r++) {
    float v[16];
    float mx = -1e30f;
#pragma unroll
    for (int tl = 0; tl < 16; tl++) { v[tl] = sacc[tl][r] * 0.125f; mx = fmaxf(mx, v[tl]); }
#pragma unroll
    for (int mk = 1; mk < 16; mk <<= 1) mx = fmaxf(mx, __shfl_xor(mx, mk, 64));
    float sum = 0.f;
#pragma unroll
    for (int tl = 0; tl < 16; tl++) { v[tl] = __expf(v[tl] - mx); sum += v[tl]; }
#pragma unroll
    for (int mk = 1; mk < 16; mk <<= 1) sum += __shfl_xor(sum, mk, 64);
    float inv = 1.f / sum;
    const int qrow = w * 16 + kq * 4 + r;
#pragma unroll
    for (int tl = 0; tl < 16; tl++) P[qrow * 264 + tl * 16 + ml] = f2bu(v[tl] * inv);
  }
  __syncthreads();

  {
    const int row_l = w * 16 + (lane >> 2);
    const int cp0 = (lane & 3) * 64;
    u16* dst = Pg + ((size_t)(b * 8 + h) * 256 + q0 + row_l) * 256 + cp0;
    const u16* srcl = &P[row_l * 264 + cp0];
#pragma unroll
    for (int i = 0; i < 8; i++) *(uint4*)(dst + i * 8) = *(const uint4*)(srcl + i * 8);
  }

  f32x4 oacc[4];
#pragma unroll
  for (int j = 0; j < 4; j++) oacc[j] = (f32x4){0.f, 0.f, 0.f, 0.f};
  for (int half = 0; half < 2; half++) {
    __syncthreads();
    {
      const u16* src = VT + ((size_t)(b * 8 + h) * 64 + srow) * 256 + half * 128 + spart * 32;
#pragma unroll
      for (int i = 0; i < 4; i++)
        *(uint4*)&kv[srow * 136 + spart * 32 + i * 8] = *(const uint4*)(src + i * 8);
    }
    __syncthreads();
#pragma unroll
    for (int st = 0; st < 4; st++) {
      short8 ap = *(const short8*)&P[(w * 16 + ml) * 264 + half * 128 + st * 32 + kq * 8];
#pragma unroll
      for (int j = 0; j < 4; j++) {
        short8 bv = *(const short8*)&kv[(j * 16 + ml) * 136 + st * 32 + kq * 8];
        oacc[j] = mfma16(ap, bv, oacc[j]);
      }
    }
  }

#pragma unroll
  for (int j = 0; j < 4; j++) {
    const int d = h * 64 + j * 16 + ml;
#pragma unroll
    for (int r = 0; r < 4; r++) {
      const int tok = b * 256 + q0 + w * 16 + kq * 4 + r;
      CTX16[(size_t)tok * 512 + d] = f2bu(oacc[j][r]);
    }
  }
}

// ---------------- attn_w = softmax(mean over heads of Pg) ----------------
__global__ __launch_bounds__(256) void k_attnw(const u16* __restrict__ Pg, float* __restrict__ AW)
{
  const int t = threadIdx.x;
  const int qt = blockIdx.x, b = blockIdx.y;
  const int row = t >> 4, seg = t & 15;
  const int q = qt * 16 + row;
  float vals[16];
#pragma unroll
  for (int i = 0; i < 16; i++) vals[i] = 0.f;
#pragma unroll
  for (int h = 0; h < 8; h++) {
    const u16* src = Pg + ((size_t)(b * 8 + h) * 256 + q) * 256 + seg * 16;
    uint4 u0 = *(const uint4*)src;
    uint4 u1 = *(const uint4*)(src + 8);
    float f0[8], f1[8];
    unp8(u0, f0); unp8(u1, f1);
#pragma unroll
    for (int i = 0; i < 8; i++) { vals[i] += f0[i]; vals[8 + i] += f1[i]; }
  }
  float vmax = -1e30f;
#pragma unroll
  for (int i = 0; i < 16; i++) { vals[i] *= 0.125f; vmax = fmaxf(vmax, vals[i]); }
#pragma unroll
  for (int mk = 1; mk < 16; mk <<= 1) vmax = fmaxf(vmax, __shfl_xor(vmax, mk, 64));
  float ssum = 0.f;
#pragma unroll
  for (int i = 0; i < 16; i++) { vals[i] = __expf(vals[i] - vmax); ssum += vals[i]; }
#pragma unroll
  for (int mk = 1; mk < 16; mk <<= 1) ssum += __shfl_xor(ssum, mk, 64);
  float inv = 1.f / ssum;
  float* orow = AW + (size_t)(b * 256 + q) * 256 + seg * 16;
#pragma unroll
  for (int i = 0; i < 16; i++) orow[i] = vals[i] * inv;
}

// ---------------- router (unchanged) ----------------
DEVFN int rwidx(int k, int e) { return k * 8 + e + (k >> 6) * 4; }

__global__ __launch_bounds__(256) void k_router(const float* __restrict__ XNp, const float* __restrict__ rw,
    const float* __restrict__ rb, float* __restrict__ gates, int* __restrict__ topi,
    int* __restrict__ cnt, float* __restrict__ imps)
{
  __shared__ float rws[4128];
  const int t = threadIdx.x;
  for (int i = t; i < 4096; i += 256) rws[rwidx(i >> 3, i & 7)] = rw[i];
  __syncthreads();
  const int w = t >> 6, l = t & 63;
  const int e = l & 7, ch = l >> 3;
  float impAcc = 0.f; int cntAcc = 0;
  const int row0 = blockIdx.x * 256 + w * 64;
  for (int r = 0; r < 64; r++) {
    const int row = row0 + r;
    const float* xr = XNp + (size_t)row * 512 + ch * 64;
    float s = 0.f;
#pragma unroll 8
    for (int j = 0; j < 64; j++) s = fmaf(xr[j], rws[rwidx(ch * 64 + j, e)], s);
    s += __shfl_xor(s, 8, 64);
    s += __shfl_xor(s, 16, 64);
    s += __shfl_xor(s, 32, 64);
    s += rb[e];
    float p[8];
#pragma unroll
    for (int i = 0; i < 8; i++) p[i] = __shfl(s, (l & 56) | i, 64);
    float mx = p[0];
#pragma unroll
    for (int i = 1; i < 8; i++) mx = fmaxf(mx, p[i]);
    float sum = 0.f;
#pragma unroll
    for (int i = 0; i < 8; i++) { p[i] = __expf(p[i] - mx); sum += p[i]; }
    float inv = 1.f / sum;
#pragma unroll
    for (int i = 0; i < 8; i++) p[i] *= inv;
    int t0 = 0; float v0 = p[0];
#pragma unroll
    for (int i = 1; i < 8; i++) if (p[i] > v0) { v0 = p[i]; t0 = i; }
    int t1 = -1; float v1 = -1.f;
#pragma unroll
    for (int i = 0; i < 8; i++) if (i != t0 && p[i] > v1) { v1 = p[i]; t1 = i; }
    if (l < 8) { impAcc += p[e]; cntAcc += (t0 == e) + (t1 == e); }
    if (l == 0) {
      gates[(size_t)row * 2] = v0; gates[(size_t)row * 2 + 1] = v1;
      topi[(size_t)row * 2] = t0;  topi[(size_t)row * 2 + 1] = t1;
    }
  }
  if (l < 8) { atomicAdd(&imps[e], impAcc); atomicAdd(&cnt[e], cntAcc); }
}

__global__ void k_scan(const int* __restrict__ cnt, int* __restrict__ basep, int* __restrict__ curs) {
  if (threadIdx.x == 0) {
    int a = 0;
    for (int e = 0; e < 8; e++) { basep[e] = a; a += cnt[e]; }
  }
  if (threadIdx.x < 8) curs[threadIdx.x] = 0;
}

__global__ __launch_bounds__(256) void k_scatter(const int* __restrict__ topi, const int* __restrict__ basep,
    int* __restrict__ cursor, int* __restrict__ rowlist, int* __restrict__ rowpos)
{
  __shared__ int lcnt[8], lbase[8];
  const int t = threadIdx.x;
  if (t < 8) lcnt[t] = 0;
  __syncthreads();
  const int token = blockIdx.x * 256 + t;
  const int e0 = topi[token * 2], e1 = topi[token * 2 + 1];
  const int p0 = atomicAdd(&lcnt[e0], 1);
  const int p1 = atomicAdd(&lcnt[e1], 1);
  __syncthreads();
  if (t < 8) lbase[t] = atomicAdd(&cursor[t], lcnt[t]);
  __syncthreads();
  const int pos0 = basep[e0] + lbase[e0] + p0;
  const int pos1 = basep[e1] + lbase[e1] + p1;
  rowlist[pos0] = token; rowlist[pos1] = token;
  rowpos[token * 2] = pos0; rowpos[token * 2 + 1] = pos1;
}

__global__ void k_loss(const int* __restrict__ cnt, const float* __restrict__ imps,
                       float* __restrict__ lossws, float* __restrict__ out, int phase) {
  if (threadIdx.x == 0 && blockIdx.x == 0) {
    float s = 0.f;
    for (int e = 0; e < 8; e++) s += ((float)cnt[e]) * imps[e];
    s *= 8.f / (8192.f * 8192.f);
    if (phase == 0) *lossws = s;
    else out[0] = *lossws + s;
  }
}

// ---------------- MFMA expert GEMM1: H = gelu(gather(XNB) @ W1[e]^T + b1[e]) bf16 ----------------
__global__ __launch_bounds__(256) void k_mg1(const u16* __restrict__ XNB, const u16* __restrict__ W1T,
    const float* __restrict__ B1, u16* __restrict__ H,
    const int* __restrict__ rowlist, const int* __restrict__ basep, const int* __restrict__ cntp)
{
  const int e = blockIdx.z;
  const int cnt = cntp[e];
  const int m0 = blockIdx.y * 128;
  if (m0 >= cnt) return;
  const int base = basep[e];
  const int n0 = blockIdx.x * 128;
  __shared__ u16 SB[16384];
  __shared__ int rl[128];
  u16* As = SB; u16* Bs = SB + 8192;
  const int t = threadIdx.x;
  if (t < 128) rl[t] = rowlist[base + min(m0 + t, cnt - 1)];
  __syncthreads();
  const int widx = t >> 6, lane = t & 63;
  const int wm = (widx & 1) * 64, wn = (widx >> 1) * 64;
  const int ml = lane & 15, kq = lane >> 4;
  const u16* wt = W1T + (size_t)e * (2048 * 512);
  const u16* agp[4]; const u16* bgp[4]; u16* alp[4]; u16* blp[4];
#pragma unroll
  for (int q = 0; q < 4; q++) {
    const int slot = q * 256 + t;
    const int row = slot >> 3;
    const int c = (slot & 7) ^ (row & 7);
    agp[q] = XNB + (size_t)rl[row] * 512 + c * 8;
    bgp[q] = wt + (size_t)(n0 + row) * 512 + c * 8;
    alp[q] = &As[(q * 256 + widx * 64) * 8];
    blp[q] = &Bs[(q * 256 + widx * 64) * 8];
  }
  f32x4 acc[4][4];
#pragma unroll
  for (int i = 0; i < 4; i++)
#pragma unroll
    for (int j = 0; j < 4; j++) acc[i][j] = (f32x4){0.f, 0.f, 0.f, 0.f};
  mma_loop(acc, agp, bgp, alp, blp, As, Bs, 512, wm, wn, ml, kq);

  __syncthreads();
  float* ep = (float*)SB + widx * (16 * 68);
  const int er = lane >> 2, ec = (lane & 3) * 16;
  const int gn = n0 + wn + ec;
  float bb[16];
#pragma unroll
  for (int u = 0; u < 4; u++) {
    float4 f = *(const float4*)(B1 + e * 2048 + gn + u * 4);
    bb[u*4]=f.x; bb[u*4+1]=f.y; bb[u*4+2]=f.z; bb[u*4+3]=f.w;
  }
#pragma unroll
  for (int i = 0; i < 4; i++) {
    float v[16];
    ep_xpose(ep, acc[i], kq, ml, er, ec, v);
    const int lr = wm + i * 16 + er;
    if (m0 + lr < cnt) {
      union { u16 h[16]; uint4 q2[2]; } pk;
#pragma unroll
      for (int u = 0; u < 16; u++) {
        float vv = v[u] + bb[u];
        float g = 0.5f * vv * (1.f + erff(vv * 0.70710678118654752f));
        pk.h[u] = f2bu(g);
      }
      u16* hp = H + (size_t)(base + m0 + lr) * 2048 + gn;
      *(uint4*)hp = pk.q2[0]; *(uint4*)(hp + 8) = pk.q2[1];
    }
  }
}

// ---------------- MFMA expert GEMM2: YB = H @ W2[e]^T + b2[e] (f32) ----------------
__global__ __launch_bounds__(256) void k_mg2(const u16* __restrict__ H, const u16* __restrict__ W2T,
    const float* __restrict__ B2, float* __restrict__ YB,
    const int* __restrict__ basep, const int* __restrict__ cntp)
{
  const int e = blockIdx.z;
  const int cnt = cntp[e];
  const int m0 = blockIdx.y * 128;
  if (m0 >= cnt) return;
  const int base = basep[e];
  const int n0 = blockIdx.x * 128;
  __shared__ u16 SB[16384];
  u16* As = SB; u16* Bs = SB + 8192;
  const int t = threadIdx.x;
  const int widx = t >> 6, lane = t & 63;
  const int wm = (widx & 1) * 64, wn = (widx >> 1) * 64;
  const int ml = lane & 15, kq = lane >> 4;
  const u16* wt = W2T + (size_t)e * (512 * 2048);
  const u16* agp[4]; const u16* bgp[4]; u16* alp[4]; u16* blp[4];
#pragma unroll
  for (int q = 0; q < 4; q++) {
    const int slot = q * 256 + t;
    const int row = slot >> 3;
    const int c = (slot & 7) ^ (row & 7);
    const int gr = min(base + m0 + row, 16383);
    agp[q] = H + (size_t)gr * 2048 + c * 8;
    bgp[q] = wt + (size_t)(n0 + row) * 2048 + c * 8;
    alp[q] = &As[(q * 256 + widx * 64) * 8];
    blp[q] = &Bs[(q * 256 + widx * 64) * 8];
  }
  f32x4 acc[4][4];
#pragma unroll
  for (int i = 0; i < 4; i++)
#pragma unroll
    for (int j = 0; j < 4; j++) acc[i][j] = (f32x4){0.f, 0.f, 0.f, 0.f};
  mma_loop(acc, agp, bgp, alp, blp, As, Bs, 2048, wm, wn, ml, kq);

  __syncthreads();
  float* ep = (float*)SB + widx * (16 * 68);
  const int er = lane >> 2, ec = (lane & 3) * 16;
  const int gn = n0 + wn + ec;
  float bb[16];
#pragma unroll
  for (int u = 0; u < 4; u++) {
    float4 f = *(const float4*)(B2 + e * 512 + gn + u * 4);
    bb[u*4]=f.x; bb[u*4+1]=f.y; bb[u*4+2]=f.z; bb[u*4+3]=f.w;
  }
#pragma unroll
  for (int i = 0; i < 4; i++) {
    float v[16];
    ep_xpose(ep, acc[i], kq, ml, er, ec, v);
    const int lr = wm + i * 16 + er;
    if (m0 + lr < cnt) {
      float* yp = YB + (size_t)(base + m0 + lr) * 512 + gn;
#pragma unroll
      for (int u = 0; u < 4; u++) {
        float4 o = {v[u*4]+bb[u*4], v[u*4+1]+bb[u*4+1], v[u*4+2]+bb[u*4+2], v[u*4+3]+bb[u*4+3]};
        *(float4*)(yp + u * 4) = o;
      }
    }
  }
}

// ---------------- combine / fv / cls ----------------
__global__ __launch_bounds__(256) void k_combine(const float* __restrict__ YB, const float* __restrict__ gates,
    const int* __restrict__ rowpos, float* __restrict__ OUT)
{
  const int idx = blockIdx.x * 256 + threadIdx.x;
  const int row = idx >> 9, d = idx & 511;
  const float g0 = gates[row * 2], g1 = gates[row * 2 + 1];
  const int r0 = rowpos[row * 2], r1 = rowpos[row * 2 + 1];
  OUT[idx] = g0 * YB[(size_t)r0 * 512 + d] + g1 * YB[(size_t)r1 * 512 + d];
}

__global__ __launch_bounds__(256) void k_fv(const float* __restrict__ O2, float* __restrict__ FVp, float* __restrict__ outv) {
  const int idx = blockIdx.x * 256 + threadIdx.x;  // 16384
  const int b = idx >> 9, d = idx & 511;
  const float* p = O2 + (size_t)b * 131072 + d;
  float s = 0.f;
  for (int i = 0; i < 256; i++) s += p[i * 512];
  s *= (1.f / 256.f);
  FVp[idx] = s;
  outv[idx] = s;
}

__global__ __launch_bounds__(256) void k_cls(const float* __restrict__ FVp, const float* __restrict__ W,
    const float* __restrict__ bias, float* __restrict__ outl) {
  const int idx = blockIdx.x * 256 + threadIdx.x;  // 16384
  const int b = idx >> 9, n = idx & 511;
  const float* f = FVp + (size_t)b * 512;
  float s = 0.f;
  for (int d = 0; d < 512; d++) s = fmaf(f[d], W[(size_t)d * 512 + n], s);
  s += bias[n];
  outl[idx] = s;
}

extern "C" void kernel_launch(void* const* d_in, const int* in_sizes, int n_in,
                              void* d_out, int out_size, void* d_ws, size_t ws_size,
                              hipStream_t stream)
{
  (void)in_sizes; (void)n_in; (void)out_size; (void)ws_size;
  const float* x    = (const float*)d_in[0];
  const float* pe_w = (const float*)d_in[1];
  const float* pe_b = (const float*)d_in[2];
  const float* pos  = (const float*)d_in[3];
  const float* ln1g = (const float*)d_in[4];
  const float* ln1b = (const float*)d_in[5];
  const float* lng[2] = {(const float*)d_in[6], (const float*)d_in[8]};
  const float* lnb[2] = {(const float*)d_in[7], (const float*)d_in[9]};
  const float* wq = (const float*)d_in[10]; const float* bq = (const float*)d_in[11];
  const float* wk = (const float*)d_in[12]; const float* bk = (const float*)d_in[13];
  const float* wv = (const float*)d_in[14]; const float* bv = (const float*)d_in[15];
  const float* wo = (const float*)d_in[16]; const float* bo = (const float*)d_in[17];
  const float* m_rw[2] = {(const float*)d_in[18], (const float*)d_in[24]};
  const float* m_rb[2] = {(const float*)d_in[19], (const float*)d_in[25]};
  const float* m_w1[2] = {(const float*)d_in[20], (const float*)d_in[26]};
  const float* m_b1[2] = {(const float*)d_in[21], (const float*)d_in[27]};
  const float* m_w2[2] = {(const float*)d_in[22], (const float*)d_in[28]};
  const float* m_b2[2] = {(const float*)d_in[23], (const float*)d_in[29]};
  const float* cls_w = (const float*)d_in[30];
  const float* cls_b = (const float*)d_in[31];

  float* ws = (float*)d_ws;
  u16* XP    = (u16*)(ws + OF_PATCH);
  float* ebuf = ws + OF_E;
  float* xn   = ws + OF_XN;
  u16* Q16   = (u16*)(ws + OF_Q16);
  u16* K16   = (u16*)(ws + OF_K16);
  u16* VTb   = (u16*)(ws + OF_VT);
  u16* ctx16 = (u16*)(ws + OF_CTX16);
  u16* peT   = (u16*)(ws + OF_PET);
  u16* wqT   = (u16*)(ws + OF_WQT);
  u16* wkT   = (u16*)(ws + OF_WKT);
  u16* wvT   = (u16*)(ws + OF_WVT);
  u16* woT   = (u16*)(ws + OF_WOT);
  u16* Pgb   = (u16*)(ws + OF_O1);   // 32MB, dead after k_attnw
  float* o1   = ws + OF_O1;
  float* o2   = ws + OF_O2;
  float* fv   = ws + OF_FV;
  float* gates = ws + OF_GATES;
  float* imps  = ws + OF_IMPS;
  int* cnt    = (int*)(ws + OF_CNT);
  int* basep  = (int*)(ws + OF_BASE);
  int* curs   = (int*)(ws + OF_CURS);
  float* lossws = ws + OF_LOSS;
  int* topi   = (int*)(ws + OF_TOPI);
  int* rowpos = (int*)(ws + OF_RPOS);
  int* rowlist= (int*)(ws + OF_RLIST);
  u16* Hbuf  = (u16*)(ws + OF_Q);    // MoE overlay on [OF_Q, OF_O1)
  float* YB  = ws + OF_PATCH;        // MoE overlay
  u16* XNB   = (u16*)(ws + OF_PATCH);// bf16 xn (XP dead post-pe-GEMM)
  u16* W1T   = (u16*)(ws + OF_O1);   // MoE overlay (after Pg dead)
  u16* W2T   = (u16*)(ws + OF_O2);

  float* out = (float*)d_out;
  float* out_logits = out;
  float* out_fv     = out + 16384;
  float* out_loss   = out + 32768;
  float* out_attnw  = out + 32769;

  // ---- dense weight prep ----
  k_wcvtd<<<dim3(20, 16), 256, 0, stream>>>(pe_w, peT, 588, 640);
  k_wcvtd<<<dim3(16, 16), 256, 0, stream>>>(wq, wqT, 512, 512);
  k_wcvtd<<<dim3(16, 16), 256, 0, stream>>>(wk, wkT, 512, 512);
  k_wcvtd<<<dim3(16, 16), 256, 0, stream>>>(wv, wvT, 512, 512);
  k_wcvtd<<<dim3(16, 16), 256, 0, stream>>>(wo, woT, 512, 512);

  k_patchify<<<20480, 256, 0, stream>>>(x, XP);
  k_bgemm<0><<<dim3(4, 64), 256, 0, stream>>>(XP, peT, pe_b, ebuf, nullptr, pos, 640);
  k_ln<<<8192, 256, 0, stream>>>(ebuf, xn, XNB, ln1g, ln1b);
  k_bgemm<1><<<dim3(4, 64), 256, 0, stream>>>(XNB, wqT, bq, nullptr, Q16, nullptr, 512);
  k_bgemm<1><<<dim3(4, 64), 256, 0, stream>>>(XNB, wkT, bk, nullptr, K16, nullptr, 512);
  k_bgemm<3><<<dim3(4, 64), 256, 0, stream>>>(XNB, wvT, bv, nullptr, VTb, nullptr, 512);
  k_fattn<<<dim3(4, 8, 32), 256, 0, stream>>>(Q16, K16, VTb, ctx16, Pgb);
  k_attnw<<<dim3(16, 32), 256, 0, stream>>>(Pgb, out_attnw);
  k_bgemm<2><<<dim3(4, 64), 256, 0, stream>>>(ctx16, woT, bo, ebuf, nullptr, nullptr, 512);

  const float* moe_in[2] = {ebuf, o1};
  float* moe_out[2] = {o1, o2};
  for (int mi = 0; mi < 2; mi++) {
    hipMemsetAsync(imps, 0, 64, stream);   // zero imps(32B) + cnt(32B)
    k_ln<<<8192, 256, 0, stream>>>(moe_in[mi], xn, XNB, lng[mi], lnb[mi]);
    // weight cvt AFTER LN: layer-2 must consume o1 before W1T overlay clobbers it
    k_wcvt<<<dim3(16, 64, 8), 256, 0, stream>>>(m_w1[mi], W1T, 512, 2048);
    k_wcvt<<<dim3(64, 16, 8), 256, 0, stream>>>(m_w2[mi], W2T, 2048, 512);
    k_router<<<32, 256, 0, stream>>>(xn, m_rw[mi], m_rb[mi], gates, topi, cnt, imps);
    k_scan<<<1, 64, 0, stream>>>(cnt, basep, curs);
    k_scatter<<<32, 256, 0, stream>>>(topi, basep, curs, rowlist, rowpos);
    k_loss<<<1, 64, 0, stream>>>(cnt, imps, lossws, out_loss, mi);
    k_mg1<<<dim3(16, 64, 8), 256, 0, stream>>>(XNB, W1T, m_b1[mi], Hbuf, rowlist, basep, cnt);
    k_mg2<<<dim3(4, 64, 8), 256, 0, stream>>>(Hbuf, W2T, m_b2[mi], YB, basep, cnt);
    k_combine<<<16384, 256, 0, stream>>>(YB, gates, rowpos, moe_out[mi]);
  }
  k_fv<<<64, 256, 0, stream>>>(o2, fv, out_fv);
  k_cls<<<64, 256, 0, stream>>>(fv, cls_w, cls_b, out_logits);
}

// Round 6
// 909.094 us; speedup vs baseline: 3.8798x; 1.1630x over previous
//
#include <hip/hip_runtime.h>
#include <hip/hip_bf16.h>

using bf16 = __hip_bfloat16;
typedef unsigned short u16;
typedef __attribute__((ext_vector_type(8))) short short8;
typedef __attribute__((ext_vector_type(4))) float f32x4;

#define DEVFN __device__ __forceinline__

DEVFN u16 f2bu(float v) { return __builtin_bit_cast(u16, __float2bfloat16(v)); }
DEVFN float us2f(u16 u) { union { unsigned int i; float f; } x; x.i = ((unsigned int)u) << 16; return x.f; }
DEVFN void unp8(uint4 u, float* f) {
  f[0]=us2f(u.x & 0xffffu); f[1]=us2f(u.x >> 16);
  f[2]=us2f(u.y & 0xffffu); f[3]=us2f(u.y >> 16);
  f[4]=us2f(u.z & 0xffffu); f[5]=us2f(u.z >> 16);
  f[6]=us2f(u.w & 0xffffu); f[7]=us2f(u.w >> 16);
}

DEVFN f32x4 mfma16(short8 a, short8 b, f32x4 c) {
  return __builtin_amdgcn_mfma_f32_16x16x32_bf16(a, b, c, 0, 0, 0);
}

// async global->LDS, 16B per lane; LDS dest = wave-uniform base + lane*16
DEVFN void gl16(const u16* g, u16* l) {
  __builtin_amdgcn_global_load_lds((const __attribute__((address_space(1))) void*)g,
                                   (__attribute__((address_space(3))) void*)l, 16, 0, 0);
}

// ---------------- workspace layout (float element offsets) ----------------
static constexpr size_t OF_PATCH = 0;          // XP bf16 [8192,640] = 2,621,440 fl ; later XNB bf16 + YB f32
static constexpr size_t OF_E     = 4816896;    // ebuf f32 [8192,512]
static constexpr size_t OF_XN    = 9011200;    // xn f32 [8192,512]
static constexpr size_t OF_Q     = 13205504;
static constexpr size_t OF_FV    = 38371328;   // 32*512
static constexpr size_t OF_GATES = 38387712;   // 8192*2
static constexpr size_t OF_IMPS  = 38404096;   // 8 f32 (memset with CNT: 64B)
static constexpr size_t OF_CNT   = 38404104;   // 8 i32
static constexpr size_t OF_BASE  = 38404112;   // 8 i32
static constexpr size_t OF_CURS  = 38404120;   // 8 i32
static constexpr size_t OF_LOSS  = 38404128;   // 1 f32 (+pad)
static constexpr size_t OF_TOPI  = 38404136;   // 8192*2 i32
static constexpr size_t OF_RPOS  = 38420520;   // 8192*2 i32
static constexpr size_t OF_RLIST = 38436904;   // 16384 i32
// Pre-MoE sublayout of [OF_Q, OF_O1):
static constexpr size_t OF_Q16   = 13205504;   // bf16 [8192,512]
static constexpr size_t OF_K16   = 15302656;
static constexpr size_t OF_VT    = 17399808;   // bf16 [32,8,64,256]
static constexpr size_t OF_CTX16 = 19496960;   // bf16 [8192,512]
static constexpr size_t OF_PET   = 21594112;   // bf16 [512,640]
static constexpr size_t OF_WQT   = 21757952;   // bf16 [512,512] each
static constexpr size_t OF_WKT   = 21889024;
static constexpr size_t OF_WVT   = 22020096;
static constexpr size_t OF_WOT   = 22151168;   // ends 22282240 < OF_O1
static constexpr size_t OF_O1    = 29982720;   // o1 f32 ; earlier Pg bf16 spans O1..FV ; W1T overlay
static constexpr size_t OF_O2    = 34177024;   // o2 f32 ; W2T overlay
// MoE overlays: H (bf16 16384x2048) on [OF_Q, OF_O1); YB f32 on [0, 8388608); XNB bf16 on [0, 2097152)

// ---------------- patchify: x[B,3,224,224] -> XP bf16 [8192,640] (zero-pad 588..639) ----------------
__global__ __launch_bounds__(256) void k_patchify(const float* __restrict__ x, u16* __restrict__ XP) {
  int idx = blockIdx.x * 256 + threadIdx.x;
  if (idx >= 8192 * 640) return;
  int row = idx / 640, j = idx - row * 640;
  u16 v = 0;
  if (j < 588) {
    int b = row >> 8, s = row & 255;
    int hh = s >> 4, ww = s & 15;
    int c = j % 3, tt = j / 3;
    int p2 = tt % 14, p1 = tt / 14;
    int src = ((b * 3 + c) * 224 + hh * 14 + p1) * 224 + (ww * 14 + p2);
    v = f2bu(x[src]);
  }
  XP[idx] = v;
}

// ---------------- dense weight cvt+transpose: W[K,512] f32 -> WT[512,KP] bf16 ----------------
__global__ __launch_bounds__(256) void k_wcvtd(const float* __restrict__ W, u16* __restrict__ WT, int K, int KP)
{
  __shared__ float s[32][33];
  const int t = threadIdx.x;
  const int tx = t & 31, ty = t >> 5;
  const int k0 = blockIdx.x * 32, n0 = blockIdx.y * 32;
#pragma unroll
  for (int i = 0; i < 4; i++) {
    int kk = k0 + ty + i * 8;
    s[ty + i * 8][tx] = (kk < K) ? W[(size_t)kk * 512 + n0 + tx] : 0.f;
  }
  __syncthreads();
#pragma unroll
  for (int i = 0; i < 4; i++) WT[(size_t)(n0 + ty + i * 8) * KP + k0 + tx] = f2bu(s[tx][ty + i * 8]);
}

// ---------------- MoE weight cvt+transpose (per expert): W[K,N] f32 -> Wt[N,K] bf16 ----------------
__global__ __launch_bounds__(256) void k_wcvt(const float* __restrict__ W, u16* __restrict__ Wt, int K, int N)
{
  __shared__ float s[32][33];
  const int t = threadIdx.x;
  const int tx = t & 31, ty = t >> 5;
  const int k0 = blockIdx.x * 32, n0 = blockIdx.y * 32;
  const size_t es = (size_t)K * N;
  const float* We = W + (size_t)blockIdx.z * es;
  u16* Wte = Wt + (size_t)blockIdx.z * es;
#pragma unroll
  for (int i = 0; i < 4; i++) s[ty + i * 8][tx] = We[(size_t)(k0 + ty + i * 8) * N + n0 + tx];
  __syncthreads();
#pragma unroll
  for (int i = 0; i < 4; i++) Wte[(size_t)(n0 + ty + i * 8) * K + k0 + tx] = f2bu(s[tx][ty + i * 8]);
}

// ======== shared MFMA engine pieces ========
DEVFN void mma_loop(f32x4 acc[4][4], const u16* const agp[4], const u16* const bgp[4],
                    u16* const alp[4], u16* const blp[4], u16* As, u16* Bs,
                    int K, int wm, int wn, int ml, int kq)
{
  for (int k0 = 0; k0 < K; k0 += 64) {
    __syncthreads();
#pragma unroll
    for (int q = 0; q < 4; q++) { gl16(agp[q] + k0, alp[q]); gl16(bgp[q] + k0, blp[q]); }
    __syncthreads();
#pragma unroll
    for (int ks = 0; ks < 2; ks++) {
      const int c = ks * 4 + kq;
      short8 af[4], bf[4];
#pragma unroll
      for (int i = 0; i < 4; i++) {
        const int row = wm + i * 16 + ml;
        af[i] = *(const short8*)&As[row * 64 + ((c ^ (row & 7)) << 3)];
      }
#pragma unroll
      for (int j = 0; j < 4; j++) {
        const int row = wn + j * 16 + ml;
        bf[j] = *(const short8*)&Bs[row * 64 + ((c ^ (row & 7)) << 3)];
      }
#pragma unroll
      for (int i = 0; i < 4; i++)
#pragma unroll
        for (int j = 0; j < 4; j++) acc[i][j] = mfma16(af[i], bf[j], acc[i][j]);
    }
  }
}

DEVFN void ep_xpose(float* ep, const f32x4* ai, int kq, int ml, int er, int ec, float* v)
{
#pragma unroll
  for (int j = 0; j < 4; j++)
#pragma unroll
    for (int r = 0; r < 4; r++)
      ep[(kq * 4 + r) * 68 + j * 16 + ml] = ai[j][r];
  __syncthreads();
#pragma unroll
  for (int u = 0; u < 4; u++) {
    float4 f = *(const float4*)&ep[er * 68 + ec + u * 4];
    v[u * 4 + 0] = f.x; v[u * 4 + 1] = f.y; v[u * 4 + 2] = f.z; v[u * 4 + 3] = f.w;
  }
  __syncthreads();
}

// ---------------- dense MFMA GEMM ----------------
template<int MODE>
__global__ __launch_bounds__(256) void k_bgemm(const u16* __restrict__ A, const u16* __restrict__ BT,
    const float* __restrict__ bias, float* __restrict__ Cf, u16* __restrict__ O16,
    const float* __restrict__ pos, int K)
{
  const int m0 = blockIdx.y * 128, n0 = blockIdx.x * 128;
  __shared__ u16 SB[16384];
  u16* As = SB; u16* Bs = SB + 8192;
  const int t = threadIdx.x;
  const int widx = t >> 6, lane = t & 63;
  const int wm = (widx & 1) * 64, wn = (widx >> 1) * 64;
  const int ml = lane & 15, kq = lane >> 4;
  const u16* agp[4]; const u16* bgp[4]; u16* alp[4]; u16* blp[4];
#pragma unroll
  for (int q = 0; q < 4; q++) {
    const int slot = q * 256 + t;
    const int row = slot >> 3;
    const int c = (slot & 7) ^ (row & 7);
    agp[q] = A + (size_t)(m0 + row) * K + c * 8;
    bgp[q] = BT + (size_t)(n0 + row) * K + c * 8;
    alp[q] = &As[(q * 256 + widx * 64) * 8];
    blp[q] = &Bs[(q * 256 + widx * 64) * 8];
  }
  f32x4 acc[4][4];
#pragma unroll
  for (int i = 0; i < 4; i++)
#pragma unroll
    for (int j = 0; j < 4; j++) acc[i][j] = (f32x4){0.f, 0.f, 0.f, 0.f};
  mma_loop(acc, agp, bgp, alp, blp, As, Bs, K, wm, wn, ml, kq);

  if (MODE == 3) {
#pragma unroll
    for (int j = 0; j < 4; j++) {
      const int n = n0 + wn + j * 16 + ml;
      const float bv = bias[n];
      const int h = n >> 6, d = n & 63;
#pragma unroll
      for (int i = 0; i < 4; i++) {
        const int mb = m0 + wm + i * 16 + kq * 4;
        const int b = mb >> 8, s0 = mb & 255;
        ushort4 w4;
        w4.x = f2bu(acc[i][j][0] + bv); w4.y = f2bu(acc[i][j][1] + bv);
        w4.z = f2bu(acc[i][j][2] + bv); w4.w = f2bu(acc[i][j][3] + bv);
        *(ushort4*)(O16 + ((size_t)(b * 8 + h) * 64 + d) * 256 + s0) = w4;
      }
    }
    return;
  }

  __syncthreads();
  float* ep = (float*)SB + widx * (16 * 68);
  const int er = lane >> 2, ec = (lane & 3) * 16;
  const int gn = n0 + wn + ec;
  float bb[16];
#pragma unroll
  for (int u = 0; u < 4; u++) {
    float4 f = *(const float4*)(bias + gn + u * 4);
    bb[u*4]=f.x; bb[u*4+1]=f.y; bb[u*4+2]=f.z; bb[u*4+3]=f.w;
  }
#pragma unroll
  for (int i = 0; i < 4; i++) {
    float v[16];
    ep_xpose(ep, acc[i], kq, ml, er, ec, v);
    const int gm = m0 + wm + i * 16 + er;
    if (MODE == 0) {
      const float* pr = pos + (size_t)(gm & 255) * 512 + gn;
      float* cp = Cf + (size_t)gm * 512 + gn;
#pragma unroll
      for (int u = 0; u < 4; u++) {
        float4 p = *(const float4*)(pr + u * 4);
        float4 o = {v[u*4]+bb[u*4]+p.x, v[u*4+1]+bb[u*4+1]+p.y, v[u*4+2]+bb[u*4+2]+p.z, v[u*4+3]+bb[u*4+3]+p.w};
        *(float4*)(cp + u * 4) = o;
      }
    } else if (MODE == 1) {
      union { u16 h[16]; uint4 q2[2]; } pk;
#pragma unroll
      for (int u = 0; u < 16; u++) pk.h[u] = f2bu(v[u] + bb[u]);
      u16* hp = O16 + (size_t)gm * 512 + gn;
      *(uint4*)hp = pk.q2[0]; *(uint4*)(hp + 8) = pk.q2[1];
    } else {  // MODE 2
      float* cp = Cf + (size_t)gm * 512 + gn;
#pragma unroll
      for (int u = 0; u < 4; u++) {
        float4 oldv = *(const float4*)(cp + u * 4);
        float4 o = {oldv.x+v[u*4]+bb[u*4], oldv.y+v[u*4+1]+bb[u*4+1], oldv.z+v[u*4+2]+bb[u*4+2], oldv.w+v[u*4+3]+bb[u*4+3]};
        *(float4*)(cp + u * 4) = o;
      }
    }
  }
}

// ---------------- LayerNorm over D=512 (writes f32 + bf16 copies) ----------------
__global__ __launch_bounds__(256) void k_ln(const float* __restrict__ X, float* __restrict__ Y,
    u16* __restrict__ YB16, const float* __restrict__ g, const float* __restrict__ b)
{
  __shared__ float red[256];
  const int row = blockIdx.x;
  const int t = threadIdx.x;
  const float* xr = X + (size_t)row * 512;
  float x0 = xr[t], x1 = xr[t + 256];
  red[t] = x0 + x1;
  __syncthreads();
  for (int s = 128; s > 0; s >>= 1) { if (t < s) red[t] += red[t + s]; __syncthreads(); }
  float mean = red[0] * (1.f / 512.f);
  __syncthreads();
  float d0 = x0 - mean, d1 = x1 - mean;
  red[t] = d0 * d0 + d1 * d1;
  __syncthreads();
  for (int s = 128; s > 0; s >>= 1) { if (t < s) red[t] += red[t + s]; __syncthreads(); }
  float rs = 1.f / sqrtf(red[0] * (1.f / 512.f) + 1e-5f);
  float y0 = d0 * rs * g[t]       + b[t];
  float y1 = d1 * rs * g[t + 256] + b[t + 256];
  float* yr = Y + (size_t)row * 512;
  yr[t] = y0; yr[t + 256] = y1;
  u16* br16 = YB16 + (size_t)row * 512;
  br16[t] = f2bu(y0); br16[t + 256] = f2bu(y1);
}

// ---------------- MFMA attention (unchanged) ----------------
__global__ __launch_bounds__(256) void k_fattn(const u16* __restrict__ Q16, const u16* __restrict__ K16,
    const u16* __restrict__ VT, u16* __restrict__ CTX16, u16* __restrict__ Pg)
{
  __shared__ u16 P[64 * 264];
  __shared__ u16 kv[64 * 136];
  const int t = threadIdx.x;
  const int qt = blockIdx.x, h = blockIdx.y, b = blockIdx.z;
  const int q0 = qt * 64;
  const int lane = t & 63, w = t >> 6;
  const int ml = lane & 15, kq = lane >> 4;
  const int srow = t >> 2, spart = t & 3;

  const size_t tokq = (size_t)(b * 256 + q0 + w * 16 + ml);
  short8 aq0 = *(const short8*)(Q16 + tokq * 512 + h * 64 + kq * 8);
  short8 aq1 = *(const short8*)(Q16 + tokq * 512 + h * 64 + 32 + kq * 8);

  f32x4 sacc[16];
#pragma unroll
  for (int i = 0; i < 16; i++) sacc[i] = (f32x4){0.f, 0.f, 0.f, 0.f};

  for (int kc = 0; kc < 4; kc++) {
    __syncthreads();
    {
      const u16* src = K16 + (size_t)(b * 256 + kc * 64 + srow) * 512 + h * 64 + spart * 16;
      uint4 v0 = *(const uint4*)src;
      uint4 v1 = *(const uint4*)(src + 8);
      *(uint4*)&kv[srow * 72 + spart * 16] = v0;
      *(uint4*)&kv[srow * 72 + spart * 16 + 8] = v1;
    }
    __syncthreads();
#pragma unroll
    for (int kt = 0; kt < 4; kt++) {
      short8 bk0 = *(const short8*)&kv[(kt * 16 + ml) * 72 + kq * 8];
      short8 bk1 = *(const short8*)&kv[(kt * 16 + ml) * 72 + 32 + kq * 8];
      sacc[kc * 4 + kt] = mfma16(aq0, bk0, sacc[kc * 4 + kt]);
      sacc[kc * 4 + kt] = mfma16(aq1, bk1, sacc[kc * 4 + kt]);
    }
  }

#pragma unroll
  for (int r = 0; r < 4; r++) {
    float v[16];
    float mx = -1e30f;
#pragma unroll
    for (int tl = 0; tl < 16; tl++) { v[tl] = sacc[tl][r] * 0.125f; mx = fmaxf(mx, v[tl]); }
#pragma unroll
    for (int mk = 1; mk < 16; mk <<= 1) mx = fmaxf(mx, __shfl_xor(mx, mk, 64));
    float sum = 0.f;
#pragma unroll
    for (int tl = 0; tl < 16; tl++) { v[tl] = __expf(v[tl] - mx); sum += v[tl]; }
#pragma unroll
    for (int mk = 1; mk < 16; mk <<= 1) sum += __shfl_xor(sum, mk, 64);
    float inv = 1.f / sum;
    const int qrow = w * 16 + kq * 4 + r;
#pragma unroll
    for (int tl = 0; tl < 16; tl++) P[qrow * 264 + tl * 16 + ml] = f2bu(v[tl] * inv);
  }
  __syncthreads();

  {
    const int row_l = w * 16 + (lane >> 2);
    const int cp0 = (lane & 3) * 64;
    u16* dst = Pg + ((size_t)(b * 8 + h) * 256 + q0 + row_l) * 256 + cp0;
    const u16* srcl = &P[row_l * 264 + cp0];
#pragma unroll
    for (int i = 0; i < 8; i++) *(uint4*)(dst + i * 8) = *(const uint4*)(srcl + i * 8);
  }

  f32x4 oacc[4];
#pragma unroll
  for (int j = 0; j < 4; j++) oacc[j] = (f32x4){0.f, 0.f, 0.f, 0.f};
  for (int half = 0; half < 2; half++) {
    __syncthreads();
    {
      const u16* src = VT + ((size_t)(b * 8 + h) * 64 + srow) * 256 + half * 128 + spart * 32;
#pragma unroll
      for (int i = 0; i < 4; i++)
        *(uint4*)&kv[srow * 136 + spart * 32 + i * 8] = *(const uint4*)(src + i * 8);
    }
    __syncthreads();
#pragma unroll
    for (int st = 0; st < 4; st++) {
      short8 ap = *(const short8*)&P[(w * 16 + ml) * 264 + half * 128 + st * 32 + kq * 8];
#pragma unroll
      for (int j = 0; j < 4; j++) {
        short8 bv = *(const short8*)&kv[(j * 16 + ml) * 136 + st * 32 + kq * 8];
        oacc[j] = mfma16(ap, bv, oacc[j]);
      }
    }
  }

#pragma unroll
  for (int j = 0; j < 4; j++) {
    const int d = h * 64 + j * 16 + ml;
#pragma unroll
    for (int r = 0; r < 4; r++) {
      const int tok = b * 256 + q0 + w * 16 + kq * 4 + r;
      CTX16[(size_t)tok * 512 + d] = f2bu(oacc[j][r]);
    }
  }
}

// ---------------- attn_w = softmax(mean over heads of Pg) ----------------
__global__ __launch_bounds__(256) void k_attnw(const u16* __restrict__ Pg, float* __restrict__ AW)
{
  const int t = threadIdx.x;
  const int qt = blockIdx.x, b = blockIdx.y;
  const int row = t >> 4, seg = t & 15;
  const int q = qt * 16 + row;
  float vals[16];
#pragma unroll
  for (int i = 0; i < 16; i++) vals[i] = 0.f;
#pragma unroll
  for (int h = 0; h < 8; h++) {
    const u16* src = Pg + ((size_t)(b * 8 + h) * 256 + q) * 256 + seg * 16;
    uint4 u0 = *(const uint4*)src;
    uint4 u1 = *(const uint4*)(src + 8);
    float f0[8], f1[8];
    unp8(u0, f0); unp8(u1, f1);
#pragma unroll
    for (int i = 0; i < 8; i++) { vals[i] += f0[i]; vals[8 + i] += f1[i]; }
  }
  float vmax = -1e30f;
#pragma unroll
  for (int i = 0; i < 16; i++) { vals[i] *= 0.125f; vmax = fmaxf(vmax, vals[i]); }
#pragma unroll
  for (int mk = 1; mk < 16; mk <<= 1) vmax = fmaxf(vmax, __shfl_xor(vmax, mk, 64));
  float ssum = 0.f;
#pragma unroll
  for (int i = 0; i < 16; i++) { vals[i] = __expf(vals[i] - vmax); ssum += vals[i]; }
#pragma unroll
  for (int mk = 1; mk < 16; mk <<= 1) ssum += __shfl_xor(ssum, mk, 64);
  float inv = 1.f / ssum;
  float* orow = AW + (size_t)(b * 256 + q) * 256 + seg * 16;
#pragma unroll
  for (int i = 0; i < 16; i++) orow[i] = vals[i] * inv;
}

// ---------------- router: 256 blocks x 32 rows (was 32 blocks x 256 rows) ----------------
DEVFN int rwidx(int k, int e) { return k * 8 + e + (k >> 6) * 4; }

__global__ __launch_bounds__(256) void k_router(const float* __restrict__ XNp, const float* __restrict__ rw,
    const float* __restrict__ rb, float* __restrict__ gates, int* __restrict__ topi,
    int* __restrict__ cnt, float* __restrict__ imps)
{
  __shared__ float rws[4128];
  const int t = threadIdx.x;
  for (int i = t; i < 4096; i += 256) rws[rwidx(i >> 3, i & 7)] = rw[i];
  __syncthreads();
  const int w = t >> 6, l = t & 63;
  const int e = l & 7, ch = l >> 3;
  float impAcc = 0.f; int cntAcc = 0;
  const int row0 = blockIdx.x * 32 + w * 8;   // 8 rows per wave
  for (int r = 0; r < 8; r++) {
    const int row = row0 + r;
    const float* xr = XNp + (size_t)row * 512 + ch * 64;
    float s = 0.f;
#pragma unroll 8
    for (int j = 0; j < 64; j++) s = fmaf(xr[j], rws[rwidx(ch * 64 + j, e)], s);
    s += __shfl_xor(s, 8, 64);
    s += __shfl_xor(s, 16, 64);
    s += __shfl_xor(s, 32, 64);
    s += rb[e];
    float p[8];
#pragma unroll
    for (int i = 0; i < 8; i++) p[i] = __shfl(s, (l & 56) | i, 64);
    float mx = p[0];
#pragma unroll
    for (int i = 1; i < 8; i++) mx = fmaxf(mx, p[i]);
    float sum = 0.f;
#pragma unroll
    for (int i = 0; i < 8; i++) { p[i] = __expf(p[i] - mx); sum += p[i]; }
    float inv = 1.f / sum;
#pragma unroll
    for (int i = 0; i < 8; i++) p[i] *= inv;
    int t0 = 0; float v0 = p[0];
#pragma unroll
    for (int i = 1; i < 8; i++) if (p[i] > v0) { v0 = p[i]; t0 = i; }
    int t1 = -1; float v1 = -1.f;
#pragma unroll
    for (int i = 0; i < 8; i++) if (i != t0 && p[i] > v1) { v1 = p[i]; t1 = i; }
    if (l < 8) { impAcc += p[e]; cntAcc += (t0 == e) + (t1 == e); }
    if (l == 0) {
      gates[(size_t)row * 2] = v0; gates[(size_t)row * 2 + 1] = v1;
      topi[(size_t)row * 2] = t0;  topi[(size_t)row * 2 + 1] = t1;
    }
  }
  if (l < 8) { atomicAdd(&imps[e], impAcc); atomicAdd(&cnt[e], cntAcc); }
}

__global__ void k_scan(const int* __restrict__ cnt, int* __restrict__ basep, int* __restrict__ curs) {
  if (threadIdx.x == 0) {
    int a = 0;
    for (int e = 0; e < 8; e++) { basep[e] = a; a += cnt[e]; }
  }
  if (threadIdx.x < 8) curs[threadIdx.x] = 0;
}

__global__ __launch_bounds__(256) void k_scatter(const int* __restrict__ topi, const int* __restrict__ basep,
    int* __restrict__ cursor, int* __restrict__ rowlist, int* __restrict__ rowpos)
{
  __shared__ int lcnt[8], lbase[8];
  const int t = threadIdx.x;
  if (t < 8) lcnt[t] = 0;
  __syncthreads();
  const int token = blockIdx.x * 256 + t;
  const int e0 = topi[token * 2], e1 = topi[token * 2 + 1];
  const int p0 = atomicAdd(&lcnt[e0], 1);
  const int p1 = atomicAdd(&lcnt[e1], 1);
  __syncthreads();
  if (t < 8) lbase[t] = atomicAdd(&cursor[t], lcnt[t]);
  __syncthreads();
  const int pos0 = basep[e0] + lbase[e0] + p0;
  const int pos1 = basep[e1] + lbase[e1] + p1;
  rowlist[pos0] = token; rowlist[pos1] = token;
  rowpos[token * 2] = pos0; rowpos[token * 2 + 1] = pos1;
}

__global__ void k_loss(const int* __restrict__ cnt, const float* __restrict__ imps,
                       float* __restrict__ lossws, float* __restrict__ out, int phase) {
  if (threadIdx.x == 0 && blockIdx.x == 0) {
    float s = 0.f;
    for (int e = 0; e < 8; e++) s += ((float)cnt[e]) * imps[e];
    s *= 8.f / (8192.f * 8192.f);
    if (phase == 0) *lossws = s;
    else out[0] = *lossws + s;
  }
}

// ---------------- MFMA expert GEMM1 ----------------
__global__ __launch_bounds__(256) void k_mg1(const u16* __restrict__ XNB, const u16* __restrict__ W1T,
    const float* __restrict__ B1, u16* __restrict__ H,
    const int* __restrict__ rowlist, const int* __restrict__ basep, const int* __restrict__ cntp)
{
  const int e = blockIdx.z;
  const int cnt = cntp[e];
  const int m0 = blockIdx.y * 128;
  if (m0 >= cnt) return;
  const int base = basep[e];
  const int n0 = blockIdx.x * 128;
  __shared__ u16 SB[16384];
  __shared__ int rl[128];
  u16* As = SB; u16* Bs = SB + 8192;
  const int t = threadIdx.x;
  if (t < 128) rl[t] = rowlist[base + min(m0 + t, cnt - 1)];
  __syncthreads();
  const int widx = t >> 6, lane = t & 63;
  const int wm = (widx & 1) * 64, wn = (widx >> 1) * 64;
  const int ml = lane & 15, kq = lane >> 4;
  const u16* wt = W1T + (size_t)e * (2048 * 512);
  const u16* agp[4]; const u16* bgp[4]; u16* alp[4]; u16* blp[4];
#pragma unroll
  for (int q = 0; q < 4; q++) {
    const int slot = q * 256 + t;
    const int row = slot >> 3;
    const int c = (slot & 7) ^ (row & 7);
    agp[q] = XNB + (size_t)rl[row] * 512 + c * 8;
    bgp[q] = wt + (size_t)(n0 + row) * 512 + c * 8;
    alp[q] = &As[(q * 256 + widx * 64) * 8];
    blp[q] = &Bs[(q * 256 + widx * 64) * 8];
  }
  f32x4 acc[4][4];
#pragma unroll
  for (int i = 0; i < 4; i++)
#pragma unroll
    for (int j = 0; j < 4; j++) acc[i][j] = (f32x4){0.f, 0.f, 0.f, 0.f};
  mma_loop(acc, agp, bgp, alp, blp, As, Bs, 512, wm, wn, ml, kq);

  __syncthreads();
  float* ep = (float*)SB + widx * (16 * 68);
  const int er = lane >> 2, ec = (lane & 3) * 16;
  const int gn = n0 + wn + ec;
  float bb[16];
#pragma unroll
  for (int u = 0; u < 4; u++) {
    float4 f = *(const float4*)(B1 + e * 2048 + gn + u * 4);
    bb[u*4]=f.x; bb[u*4+1]=f.y; bb[u*4+2]=f.z; bb[u*4+3]=f.w;
  }
#pragma unroll
  for (int i = 0; i < 4; i++) {
    float v[16];
    ep_xpose(ep, acc[i], kq, ml, er, ec, v);
    const int lr = wm + i * 16 + er;
    if (m0 + lr < cnt) {
      union { u16 h[16]; uint4 q2[2]; } pk;
#pragma unroll
      for (int u = 0; u < 16; u++) {
        float vv = v[u] + bb[u];
        float g = 0.5f * vv * (1.f + erff(vv * 0.70710678118654752f));
        pk.h[u] = f2bu(g);
      }
      u16* hp = H + (size_t)(base + m0 + lr) * 2048 + gn;
      *(uint4*)hp = pk.q2[0]; *(uint4*)(hp + 8) = pk.q2[1];
    }
  }
}

// ---------------- MFMA expert GEMM2 ----------------
__global__ __launch_bounds__(256) void k_mg2(const u16* __restrict__ H, const u16* __restrict__ W2T,
    const float* __restrict__ B2, float* __restrict__ YB,
    const int* __restrict__ basep, const int* __restrict__ cntp)
{
  const int e = blockIdx.z;
  const int cnt = cntp[e];
  const int m0 = blockIdx.y * 128;
  if (m0 >= cnt) return;
  const int base = basep[e];
  const int n0 = blockIdx.x * 128;
  __shared__ u16 SB[16384];
  u16* As = SB; u16* Bs = SB + 8192;
  const int t = threadIdx.x;
  const int widx = t >> 6, lane = t & 63;
  const int wm = (widx & 1) * 64, wn = (widx >> 1) * 64;
  const int ml = lane & 15, kq = lane >> 4;
  const u16* wt = W2T + (size_t)e * (512 * 2048);
  const u16* agp[4]; const u16* bgp[4]; u16* alp[4]; u16* blp[4];
#pragma unroll
  for (int q = 0; q < 4; q++) {
    const int slot = q * 256 + t;
    const int row = slot >> 3;
    const int c = (slot & 7) ^ (row & 7);
    const int gr = min(base + m0 + row, 16383);
    agp[q] = H + (size_t)gr * 2048 + c * 8;
    bgp[q] = wt + (size_t)(n0 + row) * 2048 + c * 8;
    alp[q] = &As[(q * 256 + widx * 64) * 8];
    blp[q] = &Bs[(q * 256 + widx * 64) * 8];
  }
  f32x4 acc[4][4];
#pragma unroll
  for (int i = 0; i < 4; i++)
#pragma unroll
    for (int j = 0; j < 4; j++) acc[i][j] = (f32x4){0.f, 0.f, 0.f, 0.f};
  mma_loop(acc, agp, bgp, alp, blp, As, Bs, 2048, wm, wn, ml, kq);

  __syncthreads();
  float* ep = (float*)SB + widx * (16 * 68);
  const int er = lane >> 2, ec = (lane & 3) * 16;
  const int gn = n0 + wn + ec;
  float bb[16];
#pragma unroll
  for (int u = 0; u < 4; u++) {
    float4 f = *(const float4*)(B2 + e * 512 + gn + u * 4);
    bb[u*4]=f.x; bb[u*4+1]=f.y; bb[u*4+2]=f.z; bb[u*4+3]=f.w;
  }
#pragma unroll
  for (int i = 0; i < 4; i++) {
    float v[16];
    ep_xpose(ep, acc[i], kq, ml, er, ec, v);
    const int lr = wm + i * 16 + er;
    if (m0 + lr < cnt) {
      float* yp = YB + (size_t)(base + m0 + lr) * 512 + gn;
#pragma unroll
      for (int u = 0; u < 4; u++) {
        float4 o = {v[u*4]+bb[u*4], v[u*4+1]+bb[u*4+1], v[u*4+2]+bb[u*4+2], v[u*4+3]+bb[u*4+3]};
        *(float4*)(yp + u * 4) = o;
      }
    }
  }
}

// ---------------- combine / fv / cls ----------------
__global__ __launch_bounds__(256) void k_combine(const float* __restrict__ YB, const float* __restrict__ gates,
    const int* __restrict__ rowpos, float* __restrict__ OUT)
{
  const int idx = blockIdx.x * 256 + threadIdx.x;
  const int row = idx >> 9, d = idx & 511;
  const float g0 = gates[row * 2], g1 = gates[row * 2 + 1];
  const int r0 = rowpos[row * 2], r1 = rowpos[row * 2 + 1];
  OUT[idx] = g0 * YB[(size_t)r0 * 512 + d] + g1 * YB[(size_t)r1 * 512 + d];
}

__global__ __launch_bounds__(256) void k_fv(const float* __restrict__ O2, float* __restrict__ FVp, float* __restrict__ outv) {
  const int idx = blockIdx.x * 256 + threadIdx.x;  // 16384
  const int b = idx >> 9, d = idx & 511;
  const float* p = O2 + (size_t)b * 131072 + d;
  float s = 0.f;
  for (int i = 0; i < 256; i++) s += p[i * 512];
  s *= (1.f / 256.f);
  FVp[idx] = s;
  outv[idx] = s;
}

__global__ __launch_bounds__(256) void k_cls(const float* __restrict__ FVp, const float* __restrict__ W,
    const float* __restrict__ bias, float* __restrict__ outl) {
  const int idx = blockIdx.x * 256 + threadIdx.x;  // 16384
  const int b = idx >> 9, n = idx & 511;
  const float* f = FVp + (size_t)b * 512;
  float s = 0.f;
  for (int d = 0; d < 512; d++) s = fmaf(f[d], W[(size_t)d * 512 + n], s);
  s += bias[n];
  outl[idx] = s;
}

extern "C" void kernel_launch(void* const* d_in, const int* in_sizes, int n_in,
                              void* d_out, int out_size, void* d_ws, size_t ws_size,
                              hipStream_t stream)
{
  (void)in_sizes; (void)n_in; (void)out_size; (void)ws_size;
  const float* x    = (const float*)d_in[0];
  const float* pe_w = (const float*)d_in[1];
  const float* pe_b = (const float*)d_in[2];
  const float* pos  = (const float*)d_in[3];
  const float* ln1g = (const float*)d_in[4];
  const float* ln1b = (const float*)d_in[5];
  const float* lng[2] = {(const float*)d_in[6], (const float*)d_in[8]};
  const float* lnb[2] = {(const float*)d_in[7], (const float*)d_in[9]};
  const float* wq = (const float*)d_in[10]; const float* bq = (const float*)d_in[11];
  const float* wk = (const float*)d_in[12]; const float* bk = (const float*)d_in[13];
  const float* wv = (const float*)d_in[14]; const float* bv = (const float*)d_in[15];
  const float* wo = (const float*)d_in[16]; const float* bo = (const float*)d_in[17];
  const float* m_rw[2] = {(const float*)d_in[18], (const float*)d_in[24]};
  const float* m_rb[2] = {(const float*)d_in[19], (const float*)d_in[25]};
  const float* m_w1[2] = {(const float*)d_in[20], (const float*)d_in[26]};
  const float* m_b1[2] = {(const float*)d_in[21], (const float*)d_in[27]};
  const float* m_w2[2] = {(const float*)d_in[22], (const float*)d_in[28]};
  const float* m_b2[2] = {(const float*)d_in[23], (const float*)d_in[29]};
  const float* cls_w = (const float*)d_in[30];
  const float* cls_b = (const float*)d_in[31];

  float* ws = (float*)d_ws;
  u16* XP    = (u16*)(ws + OF_PATCH);
  float* ebuf = ws + OF_E;
  float* xn   = ws + OF_XN;
  u16* Q16   = (u16*)(ws + OF_Q16);
  u16* K16   = (u16*)(ws + OF_K16);
  u16* VTb   = (u16*)(ws + OF_VT);
  u16* ctx16 = (u16*)(ws + OF_CTX16);
  u16* peT   = (u16*)(ws + OF_PET);
  u16* wqT   = (u16*)(ws + OF_WQT);
  u16* wkT   = (u16*)(ws + OF_WKT);
  u16* wvT   = (u16*)(ws + OF_WVT);
  u16* woT   = (u16*)(ws + OF_WOT);
  u16* Pgb   = (u16*)(ws + OF_O1);   // 32MB, dead after k_attnw
  float* o1   = ws + OF_O1;
  float* o2   = ws + OF_O2;
  float* fv   = ws + OF_FV;
  float* gates = ws + OF_GATES;
  float* imps  = ws + OF_IMPS;
  int* cnt    = (int*)(ws + OF_CNT);
  int* basep  = (int*)(ws + OF_BASE);
  int* curs   = (int*)(ws + OF_CURS);
  float* lossws = ws + OF_LOSS;
  int* topi   = (int*)(ws + OF_TOPI);
  int* rowpos = (int*)(ws + OF_RPOS);
  int* rowlist= (int*)(ws + OF_RLIST);
  u16* Hbuf  = (u16*)(ws + OF_Q);    // MoE overlay on [OF_Q, OF_O1)
  float* YB  = ws + OF_PATCH;        // MoE overlay
  u16* XNB   = (u16*)(ws + OF_PATCH);// bf16 xn (XP dead post-pe-GEMM)
  u16* W1T   = (u16*)(ws + OF_O1);   // MoE overlay (after Pg dead)
  u16* W2T   = (u16*)(ws + OF_O2);

  float* out = (float*)d_out;
  float* out_logits = out;
  float* out_fv     = out + 16384;
  float* out_loss   = out + 32768;
  float* out_attnw  = out + 32769;

  // ---- dense weight prep ----
  k_wcvtd<<<dim3(20, 16), 256, 0, stream>>>(pe_w, peT, 588, 640);
  k_wcvtd<<<dim3(16, 16), 256, 0, stream>>>(wq, wqT, 512, 512);
  k_wcvtd<<<dim3(16, 16), 256, 0, stream>>>(wk, wkT, 512, 512);
  k_wcvtd<<<dim3(16, 16), 256, 0, stream>>>(wv, wvT, 512, 512);
  k_wcvtd<<<dim3(16, 16), 256, 0, stream>>>(wo, woT, 512, 512);

  k_patchify<<<20480, 256, 0, stream>>>(x, XP);
  k_bgemm<0><<<dim3(4, 64), 256, 0, stream>>>(XP, peT, pe_b, ebuf, nullptr, pos, 640);
  k_ln<<<8192, 256, 0, stream>>>(ebuf, xn, XNB, ln1g, ln1b);
  k_bgemm<1><<<dim3(4, 64), 256, 0, stream>>>(XNB, wqT, bq, nullptr, Q16, nullptr, 512);
  k_bgemm<1><<<dim3(4, 64), 256, 0, stream>>>(XNB, wkT, bk, nullptr, K16, nullptr, 512);
  k_bgemm<3><<<dim3(4, 64), 256, 0, stream>>>(XNB, wvT, bv, nullptr, VTb, nullptr, 512);
  k_fattn<<<dim3(4, 8, 32), 256, 0, stream>>>(Q16, K16, VTb, ctx16, Pgb);
  k_attnw<<<dim3(16, 32), 256, 0, stream>>>(Pgb, out_attnw);
  k_bgemm<2><<<dim3(4, 64), 256, 0, stream>>>(ctx16, woT, bo, ebuf, nullptr, nullptr, 512);

  const float* moe_in[2] = {ebuf, o1};
  float* moe_out[2] = {o1, o2};
  for (int mi = 0; mi < 2; mi++) {
    hipMemsetAsync(imps, 0, 64, stream);   // zero imps(32B) + cnt(32B)
    k_ln<<<8192, 256, 0, stream>>>(moe_in[mi], xn, XNB, lng[mi], lnb[mi]);
    // weight cvt AFTER LN: layer-2 must consume o1 before W1T overlay clobbers it
    k_wcvt<<<dim3(16, 64, 8), 256, 0, stream>>>(m_w1[mi], W1T, 512, 2048);
    k_wcvt<<<dim3(64, 16, 8), 256, 0, stream>>>(m_w2[mi], W2T, 2048, 512);
    k_router<<<256, 256, 0, stream>>>(xn, m_rw[mi], m_rb[mi], gates, topi, cnt, imps);
    k_scan<<<1, 64, 0, stream>>>(cnt, basep, curs);
    k_scatter<<<32, 256, 0, stream>>>(topi, basep, curs, rowlist, rowpos);
    k_loss<<<1, 64, 0, stream>>>(cnt, imps, lossws, out_loss, mi);
    k_mg1<<<dim3(16, 64, 8), 256, 0, stream>>>(XNB, W1T, m_b1[mi], Hbuf, rowlist, basep, cnt);
    k_mg2<<<dim3(4, 64, 8), 256, 0, stream>>>(Hbuf, W2T, m_b2[mi], YB, basep, cnt);
    k_combine<<<16384, 256, 0, stream>>>(YB, gates, rowpos, moe_out[mi]);
  }
  k_fv<<<64, 256, 0, stream>>>(o2, fv, out_fv);
  k_cls<<<64, 256, 0, stream>>>(fv, cls_w, cls_b, out_logits);
}